// Round 1
// baseline (1582.664 us; speedup 1.0000x reference)
//
#include <hip/hip_runtime.h>

// ---------------- problem constants ----------------
#define BB 128
#define NN 4096
#define DD 64
#define SS 7
#define HH 128
#define N_ITERS 3
#define EPS_ATTN 1e-8f
#define LN_EPS 1e-5f
// scale = D^-0.5 = 0.125

typedef unsigned short ushortT;
using short8  = __attribute__((ext_vector_type(8))) short;
using floatx4 = __attribute__((ext_vector_type(4))) float;

__device__ __forceinline__ float bf2f(int u) {
    return __builtin_bit_cast(float, (unsigned)(u & 0xffff) << 16);
}
__device__ __forceinline__ ushortT f2bf(float f) {
    unsigned x = __builtin_bit_cast(unsigned, f);
    x = x + 0x7fff + ((x >> 16) & 1);   // RNE
    return (ushortT)(x >> 16);
}
__device__ __forceinline__ void wave_stats64(float x, float& mu, float& var) {
    float s1 = x, s2 = x * x;
#pragma unroll
    for (int off = 32; off > 0; off >>= 1) {
        s1 += __shfl_xor(s1, off);
        s2 += __shfl_xor(s2, off);
    }
    mu  = s1 * (1.f / 64.f);
    var = s2 * (1.f / 64.f) - mu * mu;
}

// ---------------- prep: pack weights ----------------
// Wkv bf16 [128][64] (rows 0..63 = Wk, 64..127 = Wv); transposed fp32 copies of
// W_ih/W_hh ([64][192]), mlp_w1 ([64][128]), mlp_w2 ([128][64]).
__global__ void prep_w(const float* __restrict__ Wk, const float* __restrict__ Wv,
                       const float* __restrict__ Wih, const float* __restrict__ Whh,
                       const float* __restrict__ w1, const float* __restrict__ w2,
                       ushortT* __restrict__ Wkv, float* __restrict__ WihT,
                       float* __restrict__ WhhT, float* __restrict__ w1T,
                       float* __restrict__ w2T) {
    int i = blockIdx.x * 256 + threadIdx.x;   // < 49152
    if (i < 8192) {
        float v = (i < 4096) ? Wk[i] : Wv[i - 4096];
        Wkv[i] = f2bf(v);
    } else if (i < 20480) {
        int j = i - 8192; int e = j >> 6, d = j & 63;
        WihT[d * 192 + e] = Wih[j];
    } else if (i < 32768) {
        int j = i - 20480; int e = j >> 6, d = j & 63;
        WhhT[d * 192 + e] = Whh[j];
    } else if (i < 40960) {
        int j = i - 32768; int e = j >> 6, d = j & 63;   // w1 [128][64]
        w1T[d * 128 + e] = w1[j];
    } else if (i < 49152) {
        int j = i - 40960; int e = j >> 7, h = j & 127;  // w2 [64][128]
        w2T[h * 64 + e] = w2[j];
    }
}

// ---------------- prep: slots init ----------------
__global__ void prep_slots(const float* __restrict__ nbg, const float* __restrict__ nfg,
                           const float* __restrict__ bgmu, const float* __restrict__ bgls,
                           const float* __restrict__ fmu, const float* __restrict__ fls,
                           float* __restrict__ slots) {
    int i = blockIdx.x * 256 + threadIdx.x;   // < 57344
    int d = i & 63;
    int s = (i >> 6) % 7;
    int b = i / 448;
    float v;
    if (s == 0) v = bgmu[d] + expf(bgls[d]) * nbg[b * 64 + d];
    else        v = fmu[d]  + expf(fls[d])  * nfg[(b * 6 + s - 1) * 64 + d];
    slots[i] = v;
}

// ---------------- fused LN + K/V projection (MFMA) ----------------
// 64 rows/block (4 waves x 16 rows). Per wave: LN 16 rows -> LDS bf16,
// then 16x16x32 MFMA against Wkv^T, write kv bf16 [row][128] (k=0..63, v=64..127).
__global__ __launch_bounds__(256) void kv_proj(const float* __restrict__ x,
                                               const float* __restrict__ g,
                                               const float* __restrict__ bta,
                                               const ushortT* __restrict__ Wkv,
                                               ushortT* __restrict__ kv) {
    int t = threadIdx.x, w = t >> 6, lane = t & 63;
    long row0 = ((long)blockIdx.x << 6) + (w << 4);   // this wave's 16 rows
    __shared__ ushortT lds_a[4][16][72];              // +8 pad: 2-way-only bank alias
    float gg = g[lane], bb = bta[lane];
#pragma unroll
    for (int r = 0; r < 16; ++r) {
        float xv = x[(row0 + r) * 64 + lane];
        float mu, var;
        wave_stats64(xv, mu, var);
        float xn = (xv - mu) * rsqrtf(var + LN_EPS) * gg + bb;
        lds_a[w][r][lane] = f2bf(xn);
    }
    int m = lane & 15, qd = lane >> 4;
    // B-frags direct from global: B[k=c*32+qd*8+j][n=m] = Wkv[tile*16+m][c*32+qd*8+j]
    short8 bfrag[8][2];
#pragma unroll
    for (int tt = 0; tt < 8; ++tt)
#pragma unroll
        for (int c = 0; c < 2; ++c)
            bfrag[tt][c] = *reinterpret_cast<const short8*>(
                Wkv + (tt * 16 + m) * 64 + c * 32 + qd * 8);
    __syncthreads();
    short8 afrag[2];
#pragma unroll
    for (int c = 0; c < 2; ++c)
        afrag[c] = *reinterpret_cast<const short8*>(&lds_a[w][m][c * 32 + qd * 8]);
    floatx4 acc[8];
#pragma unroll
    for (int tt = 0; tt < 8; ++tt) acc[tt] = (floatx4){0.f, 0.f, 0.f, 0.f};
#pragma unroll
    for (int tt = 0; tt < 8; ++tt)
#pragma unroll
        for (int c = 0; c < 2; ++c)
            acc[tt] = __builtin_amdgcn_mfma_f32_16x16x32_bf16(afrag[c], bfrag[tt][c],
                                                              acc[tt], 0, 0, 0);
    // D: row = qd*4 + r, col = tile*16 + m
#pragma unroll
    for (int tt = 0; tt < 8; ++tt)
#pragma unroll
        for (int r = 0; r < 4; ++r)
            kv[(row0 + qd * 4 + r) * 128 + tt * 16 + m] = f2bf(acc[tt][r]);
}

// ---------------- per-iter: slots LN + q projection (+ zero num/den) ----------------
__global__ __launch_bounds__(64) void slots_q(const float* __restrict__ slots,
                                              const float* __restrict__ Wq,
                                              const float* __restrict__ g,
                                              const float* __restrict__ bta,
                                              float* __restrict__ qbuf,
                                              float* __restrict__ num,
                                              float* __restrict__ den) {
    int b = blockIdx.x, lane = threadIdx.x;
#pragma unroll
    for (int s = 0; s < 7; ++s) num[(b * 7 + s) * 64 + lane] = 0.f;
    if (lane < 8) den[b * 8 + lane] = 0.f;
    __shared__ float WqT[64 * 65];   // [d][e], stride 65: conflict-free
    __shared__ float xn[7][64];
    for (int i = lane; i < 4096; i += 64)
        WqT[(i & 63) * 65 + (i >> 6)] = Wq[i];
    float gg = g[lane], bb = bta[lane];
#pragma unroll
    for (int s = 0; s < 7; ++s) {
        float xv = slots[(b * 7 + s) * 64 + lane];
        float mu, var;
        wave_stats64(xv, mu, var);
        xn[s][lane] = (xv - mu) * rsqrtf(var + LN_EPS) * gg + bb;
    }
    __syncthreads();
#pragma unroll
    for (int s = 0; s < 7; ++s) {
        float acc = 0.f;
#pragma unroll 8
        for (int d = 0; d < 64; ++d) acc += xn[s][d] * WqT[d * 65 + lane];
        qbuf[(b * 7 + s) * 64 + lane] = acc * 0.125f;   // fold D^-0.5
    }
}

// ---------------- per-iter: attention (logits+softmax+renorm accumulators) ----------
// One block = one (b, 256-row chunk). Phase 1 (thread-per-row): logits[7] via fp32
// FMA vs q in LDS, softmax over 7, p->bf16 LDS [s][t]; stage v^T bf16 in LDS.
// Phase 2: MFMA P[16x256]xV[256x64] (m120-verified P-as-A-operand pattern),
// atomicAdd partials into num/den.
__global__ __launch_bounds__(256) void attn_kernel(const ushortT* __restrict__ kv,
                                                   const float* __restrict__ qbuf,
                                                   float* __restrict__ num,
                                                   float* __restrict__ den) {
    int t = threadIdx.x;
    int b = blockIdx.x >> 4;
    int chunk = blockIdx.x & 15;
    long base = ((long)b << 12) + (chunk << 8);
    __shared__ float   q_lds[7][64];
    __shared__ ushortT p_lds[16][264];   // rows 7..15 read-garbage, discarded via D rows
    __shared__ ushortT vT[64][264];      // [d][r], pad 264 to spread banks
    for (int i = t; i < 448; i += 256) q_lds[i >> 6][i & 63] = qbuf[b * 448 + i];
    __syncthreads();

    {   // phase 1
        long row = base + t;
        const short8* kp = reinterpret_cast<const short8*>(kv + row * 128);
        float kx[64];
#pragma unroll
        for (int i = 0; i < 8; ++i) {
            short8 kk = kp[i];
#pragma unroll
            for (int j = 0; j < 8; ++j) kx[i * 8 + j] = bf2f(kk[j]);
        }
        float lg[7];
#pragma unroll
        for (int s = 0; s < 7; ++s) {
            float acc = 0.f;
#pragma unroll
            for (int d4 = 0; d4 < 16; ++d4) {
                float4 qv = *reinterpret_cast<const float4*>(&q_lds[s][d4 * 4]);
                acc += kx[d4 * 4 + 0] * qv.x + kx[d4 * 4 + 1] * qv.y +
                       kx[d4 * 4 + 2] * qv.z + kx[d4 * 4 + 3] * qv.w;
            }
            lg[s] = acc;
        }
        float mx = lg[0];
#pragma unroll
        for (int s = 1; s < 7; ++s) mx = fmaxf(mx, lg[s]);
        float ps[7], sum = 0.f;
#pragma unroll
        for (int s = 0; s < 7; ++s) { ps[s] = __expf(lg[s] - mx); sum += ps[s]; }
        float inv = 1.f / sum;
#pragma unroll
        for (int s = 0; s < 7; ++s) p_lds[s][t] = f2bf(ps[s] * inv + EPS_ATTN);
        // stage v^T
        const short8* vp = reinterpret_cast<const short8*>(kv + row * 128 + 64);
#pragma unroll
        for (int i = 0; i < 8; ++i) {
            short8 vv = vp[i];
#pragma unroll
            for (int j = 0; j < 8; ++j) vT[i * 8 + j][t] = (ushortT)vv[j];
        }
    }
    __syncthreads();

    // phase 2: each wave owns 16 output dims (ntile = wave)
    int w = t >> 6, lane = t & 63;
    int m = lane & 15, qd = lane >> 4;
    floatx4 acc = (floatx4){0.f, 0.f, 0.f, 0.f};
#pragma unroll
    for (int ks = 0; ks < 8; ++ks) {
        short8 af = *reinterpret_cast<const short8*>(&p_lds[m][ks * 32 + qd * 8]);
        short8 bf = *reinterpret_cast<const short8*>(&vT[w * 16 + m][ks * 32 + qd * 8]);
        acc = __builtin_amdgcn_mfma_f32_16x16x32_bf16(af, bf, acc, 0, 0, 0);
    }
#pragma unroll
    for (int r = 0; r < 4; ++r) {
        int s = qd * 4 + r;
        if (s < 7) atomicAdd(&num[((b * 7 + s) << 6) + w * 16 + m], acc[r]);
    }
    if (t < 224) {   // den partials: s = t>>5, strided sum over 256 rows
        int s = t >> 5, i0 = t & 31;
        float ds = 0.f;
#pragma unroll
        for (int r = i0; r < 256; r += 32) ds += bf2f(p_lds[s][r]);
        atomicAdd(&den[(b << 3) + s], ds);
    }
}

// ---------------- per-iter: updates/den -> GRU -> LN -> MLP -> slots ----------------
__global__ __launch_bounds__(192) void slot_update(
    const float* __restrict__ num, const float* __restrict__ den,
    float* __restrict__ slots,
    const float* __restrict__ WihT, const float* __restrict__ WhhT,
    const float* __restrict__ bih, const float* __restrict__ bhh,
    const float* __restrict__ lng, const float* __restrict__ lnb,
    const float* __restrict__ w1T, const float* __restrict__ b1,
    const float* __restrict__ w2T, const float* __restrict__ b2,
    float* __restrict__ outp, int write_out) {
    int bs = blockIdx.x, t = threadIdx.x;
    __shared__ float upd[64], hprev[64], gi[192], gh[192], hbuf[64], mn[64], m1[128];
    if (t < 64) {
        upd[t]   = num[bs * 64 + t] / den[(bs / 7) * 8 + (bs % 7)];
        hprev[t] = slots[bs * 64 + t];
    }
    __syncthreads();
    {
        float a = bih[t], h = bhh[t];
#pragma unroll 8
        for (int d = 0; d < 64; ++d) {
            a += upd[d] * WihT[d * 192 + t];
            h += hprev[d] * WhhT[d * 192 + t];
        }
        gi[t] = a; gh[t] = h;
    }
    __syncthreads();
    if (t < 64) {
        float r = 1.f / (1.f + __expf(-(gi[t] + gh[t])));
        float z = 1.f / (1.f + __expf(-(gi[64 + t] + gh[64 + t])));
        float n = tanhf(gi[128 + t] + r * gh[128 + t]);
        float h = (1.f - z) * n + z * hprev[t];
        hbuf[t] = h;
        float mu, var;
        wave_stats64(h, mu, var);
        mn[t] = (h - mu) * rsqrtf(var + LN_EPS) * lng[t] + lnb[t];
    }
    __syncthreads();
    if (t < 128) {
        float a = b1[t];
#pragma unroll 8
        for (int d = 0; d < 64; ++d) a += mn[d] * w1T[d * 128 + t];
        m1[t] = fmaxf(a, 0.f);
    }
    __syncthreads();
    if (t < 64) {
        float a = b2[t];
#pragma unroll 8
        for (int h2 = 0; h2 < 128; ++h2) a += m1[h2] * w2T[h2 * 64 + t];
        float res = hbuf[t] + a;
        slots[bs * 64 + t] = res;
        if (write_out) outp[bs * 64 + t] = res;
    }
}

// ---------------- launcher ----------------
extern "C" void kernel_launch(void* const* d_in, const int* in_sizes, int n_in,
                              void* d_out, int out_size, void* d_ws, size_t ws_size,
                              hipStream_t stream) {
    const float* inputs    = (const float*)d_in[0];
    const float* noise_bg  = (const float*)d_in[1];
    const float* noise_fg  = (const float*)d_in[2];
    const float* ln_in_g   = (const float*)d_in[3];
    const float* ln_in_b   = (const float*)d_in[4];
    const float* ln_slot_g = (const float*)d_in[5];
    const float* ln_slot_b = (const float*)d_in[6];
    const float* ln_mlp_g  = (const float*)d_in[7];
    const float* ln_mlp_b  = (const float*)d_in[8];
    const float* Wq        = (const float*)d_in[9];
    const float* Wk        = (const float*)d_in[10];
    const float* Wv        = (const float*)d_in[11];
    const float* W_ih      = (const float*)d_in[12];
    const float* W_hh      = (const float*)d_in[13];
    const float* b_ih      = (const float*)d_in[14];
    const float* b_hh      = (const float*)d_in[15];
    const float* mlp_w1    = (const float*)d_in[16];
    const float* mlp_b1    = (const float*)d_in[17];
    const float* mlp_w2    = (const float*)d_in[18];
    const float* mlp_b2    = (const float*)d_in[19];
    const float* sbg_mu    = (const float*)d_in[20];
    const float* sbg_ls    = (const float*)d_in[21];
    const float* s_mu      = (const float*)d_in[22];
    const float* s_ls      = (const float*)d_in[23];

    char* ws = (char*)d_ws;
    size_t off = 0;
    auto alloc = [&](size_t bytes) {
        void* p = ws + off;
        off += (bytes + 255) & ~(size_t)255;
        return p;
    };
    ushortT* kv   = (ushortT*)alloc((size_t)BB * NN * 128 * 2);  // 128 MiB bf16 k|v
    ushortT* Wkv  = (ushortT*)alloc(8192 * 2);
    float* slots  = (float*)alloc(57344 * 4);
    float* qbuf   = (float*)alloc(57344 * 4);
    float* num    = (float*)alloc(57344 * 4);
    float* den    = (float*)alloc(1024 * 4);
    float* WihT   = (float*)alloc(12288 * 4);
    float* WhhT   = (float*)alloc(12288 * 4);
    float* w1T    = (float*)alloc(8192 * 4);
    float* w2T    = (float*)alloc(8192 * 4);
    if (off > ws_size) return;   // fail cleanly rather than corrupt

    prep_w<<<192, 256, 0, stream>>>(Wk, Wv, W_ih, W_hh, mlp_w1, mlp_w2,
                                    Wkv, WihT, WhhT, w1T, w2T);
    prep_slots<<<224, 256, 0, stream>>>(noise_bg, noise_fg, sbg_mu, sbg_ls,
                                        s_mu, s_ls, slots);
    kv_proj<<<8192, 256, 0, stream>>>(inputs, ln_in_g, ln_in_b, Wkv, kv);
    for (int it = 0; it < N_ITERS; ++it) {
        slots_q<<<128, 64, 0, stream>>>(slots, Wq, ln_slot_g, ln_slot_b,
                                        qbuf, num, den);
        attn_kernel<<<2048, 256, 0, stream>>>(kv, qbuf, num, den);
        slot_update<<<896, 192, 0, stream>>>(num, den, slots, WihT, WhhT, b_ih, b_hh,
                                             ln_mlp_g, ln_mlp_b, w1T, mlp_b1, w2T,
                                             mlp_b2, (float*)d_out,
                                             (it == N_ITERS - 1) ? 1 : 0);
    }
}

// Round 2
// 509.540 us; speedup vs baseline: 3.1061x; 3.1061x over previous
//
#include <hip/hip_runtime.h>

// ---------------- problem constants ----------------
#define BB 128
#define NN 4096
#define DD 64
#define SS 7
#define HH 128
#define N_ITERS 3
#define EPS_ATTN 1e-8f
#define LN_EPS 1e-5f
// scale = D^-0.5 = 0.125 (folded into q)

typedef unsigned short ushortT;
using short8  = __attribute__((ext_vector_type(8))) short;
using floatx4 = __attribute__((ext_vector_type(4))) float;

__device__ __forceinline__ float bf2f(int u) {
    return __builtin_bit_cast(float, (unsigned)(u & 0xffff) << 16);
}
__device__ __forceinline__ ushortT f2bf(float f) {
    unsigned x = __builtin_bit_cast(unsigned, f);
    x = x + 0x7fff + ((x >> 16) & 1);   // RNE
    return (ushortT)(x >> 16);
}
__device__ __forceinline__ void wave_stats64(float x, float& mu, float& var) {
    float s1 = x, s2 = x * x;
#pragma unroll
    for (int off = 32; off > 0; off >>= 1) {
        s1 += __shfl_xor(s1, off);
        s2 += __shfl_xor(s2, off);
    }
    mu  = s1 * (1.f / 64.f);
    var = s2 * (1.f / 64.f) - mu * mu;
}

// ---------------- prep: pack weights ----------------
__global__ void prep_w(const float* __restrict__ Wk, const float* __restrict__ Wv,
                       const float* __restrict__ Wih, const float* __restrict__ Whh,
                       const float* __restrict__ w1, const float* __restrict__ w2,
                       ushortT* __restrict__ Wkv, float* __restrict__ WihT,
                       float* __restrict__ WhhT, float* __restrict__ w1T,
                       float* __restrict__ w2T) {
    int i = blockIdx.x * 256 + threadIdx.x;   // < 49152
    if (i < 8192) {
        float v = (i < 4096) ? Wk[i] : Wv[i - 4096];
        Wkv[i] = f2bf(v);
    } else if (i < 20480) {
        int j = i - 8192; int e = j >> 6, d = j & 63;
        WihT[d * 192 + e] = Wih[j];
    } else if (i < 32768) {
        int j = i - 20480; int e = j >> 6, d = j & 63;
        WhhT[d * 192 + e] = Whh[j];
    } else if (i < 40960) {
        int j = i - 32768; int e = j >> 6, d = j & 63;   // w1 [128][64]
        w1T[d * 128 + e] = w1[j];
    } else if (i < 49152) {
        int j = i - 40960; int e = j >> 7, h = j & 127;  // w2 [64][128]
        w2T[h * 64 + e] = w2[j];
    }
}

// ---------------- prep: slots init ----------------
__global__ void prep_slots(const float* __restrict__ nbg, const float* __restrict__ nfg,
                           const float* __restrict__ bgmu, const float* __restrict__ bgls,
                           const float* __restrict__ fmu, const float* __restrict__ fls,
                           float* __restrict__ slots) {
    int i = blockIdx.x * 256 + threadIdx.x;   // < 57344
    int d = i & 63;
    int s = (i >> 6) % 7;
    int b = i / 448;
    float v;
    if (s == 0) v = bgmu[d] + expf(bgls[d]) * nbg[b * 64 + d];
    else        v = fmu[d]  + expf(fls[d])  * nfg[(b * 6 + s - 1) * 64 + d];
    slots[i] = v;
}

// ---------------- fused LN + K/V projection (MFMA) ----------------
// 64 rows/block. Outputs:
//   k_g  [row 524288][64]  bf16 row-major
//   vT_g [row>>8][d 64][row&255] bf16 (chunk-transposed; each 128B line of a
//        d-column covers 64 rows == exactly this block's row range -> L2 merges
//        the 2B scatters into full-line writes)
__global__ __launch_bounds__(256) void kv_proj(const float* __restrict__ x,
                                               const float* __restrict__ g,
                                               const float* __restrict__ bta,
                                               const ushortT* __restrict__ Wkv,
                                               ushortT* __restrict__ kg,
                                               ushortT* __restrict__ vtg) {
    int t = threadIdx.x, w = t >> 6, lane = t & 63;
    long row0 = ((long)blockIdx.x << 6) + (w << 4);   // this wave's 16 rows
    __shared__ ushortT lds_a[4][16][72];
    float gg = g[lane], bb = bta[lane];
#pragma unroll
    for (int r = 0; r < 16; ++r) {
        float xv = x[(row0 + r) * 64 + lane];
        float mu, var;
        wave_stats64(xv, mu, var);
        float xn = (xv - mu) * rsqrtf(var + LN_EPS) * gg + bb;
        lds_a[w][r][lane] = f2bf(xn);
    }
    int m = lane & 15, qd = lane >> 4;
    short8 bfrag[8][2];
#pragma unroll
    for (int tt = 0; tt < 8; ++tt)
#pragma unroll
        for (int c = 0; c < 2; ++c)
            bfrag[tt][c] = *reinterpret_cast<const short8*>(
                Wkv + (tt * 16 + m) * 64 + c * 32 + qd * 8);
    __syncthreads();
    short8 afrag[2];
#pragma unroll
    for (int c = 0; c < 2; ++c)
        afrag[c] = *reinterpret_cast<const short8*>(&lds_a[w][m][c * 32 + qd * 8]);
    floatx4 acc[8];
#pragma unroll
    for (int tt = 0; tt < 8; ++tt) acc[tt] = (floatx4){0.f, 0.f, 0.f, 0.f};
#pragma unroll
    for (int tt = 0; tt < 8; ++tt)
#pragma unroll
        for (int c = 0; c < 2; ++c)
            acc[tt] = __builtin_amdgcn_mfma_f32_16x16x32_bf16(afrag[c], bfrag[tt][c],
                                                              acc[tt], 0, 0, 0);
    // D: row = qd*4 + r, col = tt*16 + m. cols 0..63 -> k, 64..127 -> v dim
#pragma unroll
    for (int tt = 0; tt < 8; ++tt)
#pragma unroll
        for (int r = 0; r < 4; ++r) {
            long R = row0 + qd * 4 + r;
            int col = tt * 16 + m;
            ushortT val = f2bf(acc[tt][r]);
            if (tt < 4) kg[(R << 6) + col] = val;
            else        vtg[((R >> 8) << 14) + (long)(col - 64) * 256 + (R & 255)] = val;
        }
}

// ---------------- per-iter: slots LN + q projection (+ zero num/den) ----------------
__global__ __launch_bounds__(64) void slots_q(const float* __restrict__ slots,
                                              const float* __restrict__ Wq,
                                              const float* __restrict__ g,
                                              const float* __restrict__ bta,
                                              float* __restrict__ qbuf,
                                              float* __restrict__ num,
                                              float* __restrict__ den) {
    int b = blockIdx.x, lane = threadIdx.x;
#pragma unroll
    for (int s = 0; s < 7; ++s) num[(b * 7 + s) * 64 + lane] = 0.f;
    if (lane < 8) den[b * 8 + lane] = 0.f;
    __shared__ float WqT[64 * 65];
    __shared__ float xn[7][64];
    for (int i = lane; i < 4096; i += 64)
        WqT[(i & 63) * 65 + (i >> 6)] = Wq[i];
    float gg = g[lane], bb = bta[lane];
#pragma unroll
    for (int s = 0; s < 7; ++s) {
        float xv = slots[(b * 7 + s) * 64 + lane];
        float mu, var;
        wave_stats64(xv, mu, var);
        xn[s][lane] = (xv - mu) * rsqrtf(var + LN_EPS) * gg + bb;
    }
    __syncthreads();
#pragma unroll
    for (int s = 0; s < 7; ++s) {
        float acc = 0.f;
#pragma unroll 8
        for (int d = 0; d < 64; ++d) acc += xn[s][d] * WqT[d * 65 + lane];
        qbuf[(b * 7 + s) * 64 + lane] = acc * 0.125f;   // fold D^-0.5
    }
}

// ---------------- per-iter: attention ----------------
// One block = one (b, 256-row chunk).
// Phase 1: 4 lanes per row (sub = t&3 owns dims sub*16..+16); k loads are
// short8 with 64 lanes covering 16 full 128B k-rows (perfectly coalesced).
// 2x shfl_xor reduce -> logits, softmax per 4-lane group, p -> LDS bf16.
// den accumulated in registers, wave-reduced, 7 atomics/wave.
// Phase 2: MFMA P[16x256] x V[256x64]; B-frags DIRECT from global vT_g.
__global__ __launch_bounds__(256) void attn_kernel(const ushortT* __restrict__ kg,
                                                   const ushortT* __restrict__ vtg,
                                                   const float* __restrict__ qbuf,
                                                   float* __restrict__ num,
                                                   float* __restrict__ den) {
    int t = threadIdx.x;
    int b = blockIdx.x >> 4;
    long base = ((long)blockIdx.x) << 8;          // global row of chunk start
    __shared__ float   q_lds[7][68];              // 68: row base 272B = 17*16 (aligned)
    __shared__ ushortT p_lds[16][264];            // rows 7..15 garbage, D-rows discarded
    for (int i = t; i < 448; i += 256) q_lds[i >> 6][i & 63] = qbuf[b * 448 + i];
    __syncthreads();

    int sub = t & 3, rr = t >> 2;                 // rr in [0,64)
    float dreg0 = 0.f, dreg1 = 0.f;
#pragma unroll
    for (int pass = 0; pass < 4; ++pass) {
        int row = (pass << 6) + rr;
        const short8* kp = reinterpret_cast<const short8*>(
            kg + ((base + row) << 6) + (sub << 4));
        short8 k0 = kp[0], k1 = kp[1];
        float kx[16];
#pragma unroll
        for (int j = 0; j < 8; ++j) { kx[j] = bf2f(k0[j]); kx[8 + j] = bf2f(k1[j]); }
        float lg[7];
#pragma unroll
        for (int s = 0; s < 7; ++s) {
            const float4* qp = reinterpret_cast<const float4*>(&q_lds[s][sub << 4]);
            float acc = 0.f;
#pragma unroll
            for (int c = 0; c < 4; ++c) {
                float4 qv = qp[c];
                acc += kx[c * 4 + 0] * qv.x + kx[c * 4 + 1] * qv.y +
                       kx[c * 4 + 2] * qv.z + kx[c * 4 + 3] * qv.w;
            }
            lg[s] = acc;
        }
#pragma unroll
        for (int s = 0; s < 7; ++s) {
            lg[s] += __shfl_xor(lg[s], 1);
            lg[s] += __shfl_xor(lg[s], 2);
        }
        float mx = lg[0];
#pragma unroll
        for (int s = 1; s < 7; ++s) mx = fmaxf(mx, lg[s]);
        float sum = 0.f, ps[7];
#pragma unroll
        for (int s = 0; s < 7; ++s) { ps[s] = __expf(lg[s] - mx); sum += ps[s]; }
        float inv = 1.f / sum;
        int s0 = sub * 2;
        float p0 = 0.f, p1 = 0.f;
#pragma unroll
        for (int s = 0; s < 7; ++s) {
            float pv = ps[s] * inv + EPS_ATTN;
            if (s == s0)     p0 = pv;
            if (s == s0 + 1) p1 = pv;
        }
        ushortT pb0 = f2bf(p0);
        p_lds[s0][row] = pb0;
        dreg0 += bf2f(pb0);                       // bf16-consistent with num path
        if (sub < 3) {
            ushortT pb1 = f2bf(p1);
            p_lds[s0 + 1][row] = pb1;
            dreg1 += bf2f(pb1);
        }
    }
    // den: reduce over lanes sharing sub (xor 4..32), then 7 atomics per wave
#pragma unroll
    for (int off = 4; off < 64; off <<= 1) {
        dreg0 += __shfl_xor(dreg0, off);
        dreg1 += __shfl_xor(dreg1, off);
    }
    if ((t & 63) < 4) {
        int s0 = (t & 3) * 2;
        atomicAdd(&den[(b << 3) + s0], dreg0);
        if (s0 < 6) atomicAdd(&den[(b << 3) + s0 + 1], dreg1);
    }
    __syncthreads();

    // phase 2: each wave owns 16 output dims; B-frags straight from global vT_g
    int w = t >> 6, lane = t & 63;
    int m = lane & 15, qd = lane >> 4;
    const ushortT* vb = vtg + (((long)blockIdx.x) << 14) + (long)(w * 16 + m) * 256;
    floatx4 acc = (floatx4){0.f, 0.f, 0.f, 0.f};
#pragma unroll
    for (int ks = 0; ks < 8; ++ks) {
        short8 af = *reinterpret_cast<const short8*>(&p_lds[m][ks * 32 + qd * 8]);
        short8 bf = *reinterpret_cast<const short8*>(vb + ks * 32 + qd * 8);
        acc = __builtin_amdgcn_mfma_f32_16x16x32_bf16(af, bf, acc, 0, 0, 0);
    }
#pragma unroll
    for (int r = 0; r < 4; ++r) {
        int s = qd * 4 + r;
        if (s < 7) atomicAdd(&num[((b * 7 + s) << 6) + w * 16 + m], acc[r]);
    }
}

// ---------------- per-iter: updates/den -> GRU -> LN -> MLP -> slots ----------------
__global__ __launch_bounds__(192) void slot_update(
    const float* __restrict__ num, const float* __restrict__ den,
    float* __restrict__ slots,
    const float* __restrict__ WihT, const float* __restrict__ WhhT,
    const float* __restrict__ bih, const float* __restrict__ bhh,
    const float* __restrict__ lng, const float* __restrict__ lnb,
    const float* __restrict__ w1T, const float* __restrict__ b1,
    const float* __restrict__ w2T, const float* __restrict__ b2,
    float* __restrict__ outp, int write_out) {
    int bs = blockIdx.x, t = threadIdx.x;
    __shared__ float upd[64], hprev[64], gi[192], gh[192], hbuf[64], mn[64], m1[128];
    if (t < 64) {
        upd[t]   = num[bs * 64 + t] / den[(bs / 7) * 8 + (bs % 7)];
        hprev[t] = slots[bs * 64 + t];
    }
    __syncthreads();
    {
        float a = bih[t], h = bhh[t];
#pragma unroll 8
        for (int d = 0; d < 64; ++d) {
            a += upd[d] * WihT[d * 192 + t];
            h += hprev[d] * WhhT[d * 192 + t];
        }
        gi[t] = a; gh[t] = h;
    }
    __syncthreads();
    if (t < 64) {
        float r = 1.f / (1.f + __expf(-(gi[t] + gh[t])));
        float z = 1.f / (1.f + __expf(-(gi[64 + t] + gh[64 + t])));
        float n = tanhf(gi[128 + t] + r * gh[128 + t]);
        float h = (1.f - z) * n + z * hprev[t];
        hbuf[t] = h;
        float mu, var;
        wave_stats64(h, mu, var);
        mn[t] = (h - mu) * rsqrtf(var + LN_EPS) * lng[t] + lnb[t];
    }
    __syncthreads();
    if (t < 128) {
        float a = b1[t];
#pragma unroll 8
        for (int d = 0; d < 64; ++d) a += mn[d] * w1T[d * 128 + t];
        m1[t] = fmaxf(a, 0.f);
    }
    __syncthreads();
    if (t < 64) {
        float a = b2[t];
#pragma unroll 8
        for (int h2 = 0; h2 < 128; ++h2) a += m1[h2] * w2T[h2 * 64 + t];
        float res = hbuf[t] + a;
        slots[bs * 64 + t] = res;
        if (write_out) outp[bs * 64 + t] = res;
    }
}

// ---------------- launcher ----------------
extern "C" void kernel_launch(void* const* d_in, const int* in_sizes, int n_in,
                              void* d_out, int out_size, void* d_ws, size_t ws_size,
                              hipStream_t stream) {
    const float* inputs    = (const float*)d_in[0];
    const float* noise_bg  = (const float*)d_in[1];
    const float* noise_fg  = (const float*)d_in[2];
    const float* ln_in_g   = (const float*)d_in[3];
    const float* ln_in_b   = (const float*)d_in[4];
    const float* ln_slot_g = (const float*)d_in[5];
    const float* ln_slot_b = (const float*)d_in[6];
    const float* ln_mlp_g  = (const float*)d_in[7];
    const float* ln_mlp_b  = (const float*)d_in[8];
    const float* Wq        = (const float*)d_in[9];
    const float* Wk        = (const float*)d_in[10];
    const float* Wv        = (const float*)d_in[11];
    const float* W_ih      = (const float*)d_in[12];
    const float* W_hh      = (const float*)d_in[13];
    const float* b_ih      = (const float*)d_in[14];
    const float* b_hh      = (const float*)d_in[15];
    const float* mlp_w1    = (const float*)d_in[16];
    const float* mlp_b1    = (const float*)d_in[17];
    const float* mlp_w2    = (const float*)d_in[18];
    const float* mlp_b2    = (const float*)d_in[19];
    const float* sbg_mu    = (const float*)d_in[20];
    const float* sbg_ls    = (const float*)d_in[21];
    const float* s_mu      = (const float*)d_in[22];
    const float* s_ls      = (const float*)d_in[23];

    char* ws = (char*)d_ws;
    size_t off = 0;
    auto alloc = [&](size_t bytes) {
        void* p = ws + off;
        off += (bytes + 255) & ~(size_t)255;
        return p;
    };
    ushortT* kg   = (ushortT*)alloc((size_t)BB * NN * 64 * 2);   // 64 MiB k row-major
    ushortT* vtg  = (ushortT*)alloc((size_t)BB * NN * 64 * 2);   // 64 MiB v transposed
    ushortT* Wkv  = (ushortT*)alloc(8192 * 2);
    float* slots  = (float*)alloc(57344 * 4);
    float* qbuf   = (float*)alloc(57344 * 4);
    float* num    = (float*)alloc(57344 * 4);
    float* den    = (float*)alloc(1024 * 4);
    float* WihT   = (float*)alloc(12288 * 4);
    float* WhhT   = (float*)alloc(12288 * 4);
    float* w1T    = (float*)alloc(8192 * 4);
    float* w2T    = (float*)alloc(8192 * 4);
    if (off > ws_size) return;

    prep_w<<<192, 256, 0, stream>>>(Wk, Wv, W_ih, W_hh, mlp_w1, mlp_w2,
                                    Wkv, WihT, WhhT, w1T, w2T);
    prep_slots<<<224, 256, 0, stream>>>(noise_bg, noise_fg, sbg_mu, sbg_ls,
                                        s_mu, s_ls, slots);
    kv_proj<<<8192, 256, 0, stream>>>(inputs, ln_in_g, ln_in_b, Wkv, kg, vtg);
    for (int it = 0; it < N_ITERS; ++it) {
        slots_q<<<128, 64, 0, stream>>>(slots, Wq, ln_slot_g, ln_slot_b,
                                        qbuf, num, den);
        attn_kernel<<<2048, 256, 0, stream>>>(kg, vtg, qbuf, num, den);
        slot_update<<<896, 192, 0, stream>>>(num, den, slots, WihT, WhhT, b_ih, b_hh,
                                             ln_mlp_g, ln_mlp_b, w1T, mlp_b1, w2T,
                                             mlp_b2, (float*)d_out,
                                             (it == N_ITERS - 1) ? 1 : 0);
    }
}

// Round 3
// 429.316 us; speedup vs baseline: 3.6865x; 1.1869x over previous
//
#include <hip/hip_runtime.h>

// ---------------- problem constants ----------------
#define BB 128
#define NN 4096
#define DD 64
#define SS 7
#define HH 128
#define N_ITERS 3
#define EPS_ATTN 1e-8f
#define LN_EPS 1e-5f
// scale = D^-0.5 = 0.125 (folded into q)

typedef unsigned short ushortT;
using short8  = __attribute__((ext_vector_type(8))) short;
using floatx4 = __attribute__((ext_vector_type(4))) float;

__device__ __forceinline__ float bf2f(int u) {
    return __builtin_bit_cast(float, (unsigned)(u & 0xffff) << 16);
}
__device__ __forceinline__ ushortT f2bf(float f) {
    unsigned x = __builtin_bit_cast(unsigned, f);
    x = x + 0x7fff + ((x >> 16) & 1);   // RNE
    return (ushortT)(x >> 16);
}
__device__ __forceinline__ void wave_stats64(float x, float& mu, float& var) {
    float s1 = x, s2 = x * x;
#pragma unroll
    for (int off = 32; off > 0; off >>= 1) {
        s1 += __shfl_xor(s1, off);
        s2 += __shfl_xor(s2, off);
    }
    mu  = s1 * (1.f / 64.f);
    var = s2 * (1.f / 64.f) - mu * mu;
}

// ---------------- prep: pack weights ----------------
__global__ void prep_w(const float* __restrict__ Wk, const float* __restrict__ Wv,
                       const float* __restrict__ Wih, const float* __restrict__ Whh,
                       const float* __restrict__ w1, const float* __restrict__ w2,
                       ushortT* __restrict__ Wkv, float* __restrict__ WihT,
                       float* __restrict__ WhhT, float* __restrict__ w1T,
                       float* __restrict__ w2T) {
    int i = blockIdx.x * 256 + threadIdx.x;   // < 49152
    if (i < 8192) {
        float v = (i < 4096) ? Wk[i] : Wv[i - 4096];
        Wkv[i] = f2bf(v);
    } else if (i < 20480) {
        int j = i - 8192; int e = j >> 6, d = j & 63;
        WihT[d * 192 + e] = Wih[j];
    } else if (i < 32768) {
        int j = i - 20480; int e = j >> 6, d = j & 63;
        WhhT[d * 192 + e] = Whh[j];
    } else if (i < 40960) {
        int j = i - 32768; int e = j >> 6, d = j & 63;   // w1 [128][64]
        w1T[d * 128 + e] = w1[j];
    } else if (i < 49152) {
        int j = i - 40960; int e = j >> 7, h = j & 127;  // w2 [64][128]
        w2T[h * 64 + e] = w2[j];
    }
}

// ---------------- prep: slots init ----------------
__global__ void prep_slots(const float* __restrict__ nbg, const float* __restrict__ nfg,
                           const float* __restrict__ bgmu, const float* __restrict__ bgls,
                           const float* __restrict__ fmu, const float* __restrict__ fls,
                           float* __restrict__ slots) {
    int i = blockIdx.x * 256 + threadIdx.x;   // < 57344
    int d = i & 63;
    int s = (i >> 6) % 7;
    int b = i / 448;
    float v;
    if (s == 0) v = bgmu[d] + expf(bgls[d]) * nbg[b * 64 + d];
    else        v = fmu[d]  + expf(fls[d])  * nfg[(b * 6 + s - 1) * 64 + d];
    slots[i] = v;
}

// ---------------- fused LN + K/V projection (MFMA) ----------------
// 64 rows/block, grid 8192. LN: 4 lanes/row (coalesced float4 loads, 2 shfl
// rounds). k-half MFMA uses SWAPPED operands (bfrag as A, xn as B) so D is
// transposed -> lane holds 4 consecutive cols of one row -> 8B packed store.
// v-half normal orientation -> 4 consecutive chunk-rows per lane -> 8B store.
// Outputs: kg [row][64] bf16; vtg [row>>7][d][row&127] bf16 (128-row chunks).
__global__ __launch_bounds__(256) void kv_proj(const float* __restrict__ x,
                                               const float* __restrict__ g,
                                               const float* __restrict__ bta,
                                               const ushortT* __restrict__ Wkv,
                                               ushortT* __restrict__ kg,
                                               ushortT* __restrict__ vtg) {
    int t = threadIdx.x, w = t >> 6, lane = t & 63;
    long row0 = (long)blockIdx.x << 6;
    int sub = t & 3, r = t >> 2;                    // 4 lanes per row, r in [0,64)
    __shared__ ushortT lds_a[64][72];               // 144B row stride (16B-aligned)

    // phase 1: LN, 16 dims per lane
    const float* xr = x + (row0 + r) * 64 + sub * 16;
    float4 xa[4];
#pragma unroll
    for (int c = 0; c < 4; ++c) xa[c] = *reinterpret_cast<const float4*>(xr + c * 4);
    float s1 = 0.f, s2 = 0.f;
#pragma unroll
    for (int c = 0; c < 4; ++c) {
        s1 += xa[c].x + xa[c].y + xa[c].z + xa[c].w;
        s2 += xa[c].x * xa[c].x + xa[c].y * xa[c].y +
              xa[c].z * xa[c].z + xa[c].w * xa[c].w;
    }
    s1 += __shfl_xor(s1, 1); s2 += __shfl_xor(s2, 1);
    s1 += __shfl_xor(s1, 2); s2 += __shfl_xor(s2, 2);
    float mu = s1 * (1.f / 64.f);
    float var = s2 * (1.f / 64.f) - mu * mu;
    float rs = rsqrtf(var + LN_EPS);
    unsigned un[8];
#pragma unroll
    for (int c = 0; c < 4; ++c) {
        float4 g4 = *reinterpret_cast<const float4*>(g + sub * 16 + c * 4);
        float4 b4 = *reinterpret_cast<const float4*>(bta + sub * 16 + c * 4);
        float n0 = (xa[c].x - mu) * rs * g4.x + b4.x;
        float n1 = (xa[c].y - mu) * rs * g4.y + b4.y;
        float n2 = (xa[c].z - mu) * rs * g4.z + b4.z;
        float n3 = (xa[c].w - mu) * rs * g4.w + b4.w;
        un[c * 2]     = (unsigned)f2bf(n0) | ((unsigned)f2bf(n1) << 16);
        un[c * 2 + 1] = (unsigned)f2bf(n2) | ((unsigned)f2bf(n3) << 16);
    }
    *reinterpret_cast<uint4*>(&lds_a[r][sub * 16]) =
        make_uint4(un[0], un[1], un[2], un[3]);
    *reinterpret_cast<uint4*>(&lds_a[r][sub * 16 + 8]) =
        make_uint4(un[4], un[5], un[6], un[7]);

    int m = lane & 15, qd = lane >> 4;
    // k-half weight frags (issued before barrier; L2-hot broadcast)
    short8 bk[4][2];
#pragma unroll
    for (int tt = 0; tt < 4; ++tt)
#pragma unroll
        for (int c = 0; c < 2; ++c)
            bk[tt][c] = *reinterpret_cast<const short8*>(
                Wkv + (tt * 16 + m) * 64 + c * 32 + qd * 8);
    __syncthreads();

    short8 af[2];
#pragma unroll
    for (int c = 0; c < 2; ++c)
        af[c] = *reinterpret_cast<const short8*>(&lds_a[w * 16 + m][c * 32 + qd * 8]);

    // k-half: swapped operands -> D' = Wk_tile . xn^T (transposed tile)
    floatx4 ak[4];
#pragma unroll
    for (int tt = 0; tt < 4; ++tt) ak[tt] = (floatx4){0.f, 0.f, 0.f, 0.f};
#pragma unroll
    for (int tt = 0; tt < 4; ++tt)
#pragma unroll
        for (int c = 0; c < 2; ++c)
            ak[tt] = __builtin_amdgcn_mfma_f32_16x16x32_bf16(bk[tt][c], af[c],
                                                             ak[tt], 0, 0, 0);
    // v-half: normal orientation
    short8 bv[4][2];
#pragma unroll
    for (int tt = 0; tt < 4; ++tt)
#pragma unroll
        for (int c = 0; c < 2; ++c)
            bv[tt][c] = *reinterpret_cast<const short8*>(
                Wkv + ((tt + 4) * 16 + m) * 64 + c * 32 + qd * 8);
    floatx4 av[4];
#pragma unroll
    for (int tt = 0; tt < 4; ++tt) av[tt] = (floatx4){0.f, 0.f, 0.f, 0.f};
#pragma unroll
    for (int tt = 0; tt < 4; ++tt)
#pragma unroll
        for (int c = 0; c < 2; ++c)
            av[tt] = __builtin_amdgcn_mfma_f32_16x16x32_bf16(af[c], bv[tt][c],
                                                             av[tt], 0, 0, 0);
    // k stores: lane owns row (row0 + w*16 + m), cols tt*16 + qd*4 .. +4
    long Rk = row0 + w * 16 + m;
#pragma unroll
    for (int tt = 0; tt < 4; ++tt) {
        uint2 u;
        u.x = (unsigned)f2bf(ak[tt][0]) | ((unsigned)f2bf(ak[tt][1]) << 16);
        u.y = (unsigned)f2bf(ak[tt][2]) | ((unsigned)f2bf(ak[tt][3]) << 16);
        *reinterpret_cast<uint2*>(kg + (Rk << 6) + tt * 16 + qd * 4) = u;
    }
    // v stores: lane owns d = tt*16+m, chunk-rows rv .. rv+4
    long vchunk = ((long)(blockIdx.x >> 1)) << 13;    // *8192
    int rv = (int)(row0 & 127) + w * 16 + qd * 4;
#pragma unroll
    for (int tt = 0; tt < 4; ++tt) {
        int d = tt * 16 + m;
        uint2 u;
        u.x = (unsigned)f2bf(av[tt][0]) | ((unsigned)f2bf(av[tt][1]) << 16);
        u.y = (unsigned)f2bf(av[tt][2]) | ((unsigned)f2bf(av[tt][3]) << 16);
        *reinterpret_cast<uint2*>(vtg + vchunk + d * 128 + rv) = u;
    }
}

// ---------------- per-iter: slots LN + q projection ----------------
__global__ __launch_bounds__(448) void slots_q(const float* __restrict__ slots,
                                               const float* __restrict__ Wq,
                                               const float* __restrict__ g,
                                               const float* __restrict__ bta,
                                               float* __restrict__ qbuf) {
    int b = blockIdx.x, t = threadIdx.x, s = t >> 6, lane = t & 63;
    __shared__ float WqT[64 * 65];
    __shared__ float xn[7][64];
    for (int i = t; i < 4096; i += 448)
        WqT[(i & 63) * 65 + (i >> 6)] = Wq[i];
    float xv = slots[(b * 7 + s) * 64 + lane];
    float mu, var;
    wave_stats64(xv, mu, var);
    xn[s][lane] = (xv - mu) * rsqrtf(var + LN_EPS) * g[lane] + bta[lane];
    __syncthreads();
    float acc = 0.f;
#pragma unroll 8
    for (int d = 0; d < 64; ++d) acc += xn[s][d] * WqT[d * 65 + lane];
    qbuf[(b * 7 + s) * 64 + lane] = acc * 0.125f;   // fold D^-0.5
}

// ---------------- per-iter: attention (no atomics; per-chunk partials) -----
// One block = one 128-row chunk (grid 4096 = 32 chunks/b). Prefetch k + v
// fragments to registers first, then softmax, p->LDS bf16, MFMA P[16x128] x
// V[128x64], write num/den partials (plain stores).
__global__ __launch_bounds__(256) void attn_kernel(const ushortT* __restrict__ kg,
                                                   const ushortT* __restrict__ vtg,
                                                   const float* __restrict__ qbuf,
                                                   float* __restrict__ num_p,
                                                   float* __restrict__ den_p) {
    int t = threadIdx.x;
    int ck = blockIdx.x;                 // global chunk
    int b = ck >> 5;
    long base = (long)ck << 7;
    __shared__ float   q_lds[7][68];
    __shared__ ushortT p_lds[16][136];   // rows 7..15 garbage (D rows discarded)
    __shared__ float   den_w[4][8];
    int w = t >> 6, lane = t & 63, m = lane & 15, qd = lane >> 4;
    int sub = t & 3, rr = t >> 2;

    // prefetch k rows (2 passes x 32B) — fully coalesced
    short8 kf[2][2];
#pragma unroll
    for (int p = 0; p < 2; ++p) {
        const short8* kp = reinterpret_cast<const short8*>(
            kg + ((base + p * 64 + rr) << 6) + (sub << 4));
        kf[p][0] = kp[0];
        kf[p][1] = kp[1];
    }
    // prefetch v B-frags straight from transposed global
    const ushortT* vb = vtg + ((long)ck << 13) + (long)(w * 16 + m) * 128;
    short8 bf[4];
#pragma unroll
    for (int ks = 0; ks < 4; ++ks)
        bf[ks] = *reinterpret_cast<const short8*>(vb + ks * 32 + qd * 8);
    for (int i = t; i < 448; i += 256) q_lds[i >> 6][i & 63] = qbuf[b * 448 + i];
    __syncthreads();

    float dreg0 = 0.f, dreg1 = 0.f;
    int s0 = sub * 2;
#pragma unroll
    for (int p = 0; p < 2; ++p) {
        int row = p * 64 + rr;
        float kx[16];
#pragma unroll
        for (int j = 0; j < 8; ++j) {
            kx[j]     = bf2f(kf[p][0][j]);
            kx[8 + j] = bf2f(kf[p][1][j]);
        }
        float lg[7];
#pragma unroll
        for (int s = 0; s < 7; ++s) {
            const float4* qp = reinterpret_cast<const float4*>(&q_lds[s][sub << 4]);
            float acc = 0.f;
#pragma unroll
            for (int c = 0; c < 4; ++c) {
                float4 qv = qp[c];
                acc += kx[c * 4 + 0] * qv.x + kx[c * 4 + 1] * qv.y +
                       kx[c * 4 + 2] * qv.z + kx[c * 4 + 3] * qv.w;
            }
            lg[s] = acc;
        }
#pragma unroll
        for (int s = 0; s < 7; ++s) {
            lg[s] += __shfl_xor(lg[s], 1);
            lg[s] += __shfl_xor(lg[s], 2);
        }
        float mx = lg[0];
#pragma unroll
        for (int s = 1; s < 7; ++s) mx = fmaxf(mx, lg[s]);
        float sum = 0.f, ps[7];
#pragma unroll
        for (int s = 0; s < 7; ++s) { ps[s] = __expf(lg[s] - mx); sum += ps[s]; }
        float inv = 1.f / sum;
        float p0 = 0.f, p1 = 0.f;
#pragma unroll
        for (int s = 0; s < 7; ++s) {
            float pv = ps[s] * inv + EPS_ATTN;
            if (s == s0)     p0 = pv;
            if (s == s0 + 1) p1 = pv;
        }
        ushortT pb0 = f2bf(p0);
        p_lds[s0][row] = pb0;
        dreg0 += bf2f(pb0);
        if (sub < 3) {
            ushortT pb1 = f2bf(p1);
            p_lds[s0 + 1][row] = pb1;
            dreg1 += bf2f(pb1);
        }
    }
#pragma unroll
    for (int off = 4; off < 64; off <<= 1) {
        dreg0 += __shfl_xor(dreg0, off);
        dreg1 += __shfl_xor(dreg1, off);
    }
    if (lane < 4) {
        den_w[w][2 * lane] = dreg0;
        if (lane < 3) den_w[w][2 * lane + 1] = dreg1;
    }
    __syncthreads();

    floatx4 acc = (floatx4){0.f, 0.f, 0.f, 0.f};
#pragma unroll
    for (int ks = 0; ks < 4; ++ks) {
        short8 af = *reinterpret_cast<const short8*>(&p_lds[m][ks * 32 + qd * 8]);
        acc = __builtin_amdgcn_mfma_f32_16x16x32_bf16(af, bf[ks], acc, 0, 0, 0);
    }
#pragma unroll
    for (int r = 0; r < 4; ++r) {
        int s = qd * 4 + r;
        if (s < 7) num_p[((long)ck * 7 + s) * 64 + w * 16 + m] = acc[r];
    }
    if (t < 7) den_p[ck * 8 + t] = den_w[0][t] + den_w[1][t] + den_w[2][t] + den_w[3][t];
}

// ---------------- per-iter: reduce partials -> GRU -> LN -> MLP -> slots ----
__global__ __launch_bounds__(192) void slot_update(
    const float* __restrict__ num_p, const float* __restrict__ den_p,
    float* __restrict__ slots,
    const float* __restrict__ WihT, const float* __restrict__ WhhT,
    const float* __restrict__ bih, const float* __restrict__ bhh,
    const float* __restrict__ lng, const float* __restrict__ lnb,
    const float* __restrict__ w1T, const float* __restrict__ b1,
    const float* __restrict__ w2T, const float* __restrict__ b2,
    float* __restrict__ outp, int write_out) {
    int bs = blockIdx.x, t = threadIdx.x;
    int b = bs / 7, s = bs % 7;
    __shared__ float upd[64], hprev[64], gi[192], gh[192], hbuf[64], mn[64], m1[128];
    if (t < 64) {
        float nsum = 0.f, dsum = 0.f;
#pragma unroll 4
        for (int c = 0; c < 32; ++c) {
            nsum += num_p[((long)(b * 32 + c) * 7 + s) * 64 + t];
            dsum += den_p[(b * 32 + c) * 8 + s];
        }
        upd[t]   = nsum / dsum;
        hprev[t] = slots[bs * 64 + t];
    }
    __syncthreads();
    {
        float a = bih[t], h = bhh[t];
#pragma unroll 8
        for (int d = 0; d < 64; ++d) {
            a += upd[d] * WihT[d * 192 + t];
            h += hprev[d] * WhhT[d * 192 + t];
        }
        gi[t] = a; gh[t] = h;
    }
    __syncthreads();
    if (t < 64) {
        float r = 1.f / (1.f + __expf(-(gi[t] + gh[t])));
        float z = 1.f / (1.f + __expf(-(gi[64 + t] + gh[64 + t])));
        float n = tanhf(gi[128 + t] + r * gh[128 + t]);
        float h = (1.f - z) * n + z * hprev[t];
        hbuf[t] = h;
        float mu, var;
        wave_stats64(h, mu, var);
        mn[t] = (h - mu) * rsqrtf(var + LN_EPS) * lng[t] + lnb[t];
    }
    __syncthreads();
    if (t < 128) {
        float a = b1[t];
#pragma unroll 8
        for (int d = 0; d < 64; ++d) a += mn[d] * w1T[d * 128 + t];
        m1[t] = fmaxf(a, 0.f);
    }
    __syncthreads();
    if (t < 64) {
        float a = b2[t];
#pragma unroll 8
        for (int h2 = 0; h2 < 128; ++h2) a += m1[h2] * w2T[h2 * 64 + t];
        float res = hbuf[t] + a;
        slots[bs * 64 + t] = res;
        if (write_out) outp[bs * 64 + t] = res;
    }
}

// ---------------- launcher ----------------
extern "C" void kernel_launch(void* const* d_in, const int* in_sizes, int n_in,
                              void* d_out, int out_size, void* d_ws, size_t ws_size,
                              hipStream_t stream) {
    const float* inputs    = (const float*)d_in[0];
    const float* noise_bg  = (const float*)d_in[1];
    const float* noise_fg  = (const float*)d_in[2];
    const float* ln_in_g   = (const float*)d_in[3];
    const float* ln_in_b   = (const float*)d_in[4];
    const float* ln_slot_g = (const float*)d_in[5];
    const float* ln_slot_b = (const float*)d_in[6];
    const float* ln_mlp_g  = (const float*)d_in[7];
    const float* ln_mlp_b  = (const float*)d_in[8];
    const float* Wq        = (const float*)d_in[9];
    const float* Wk        = (const float*)d_in[10];
    const float* Wv        = (const float*)d_in[11];
    const float* W_ih      = (const float*)d_in[12];
    const float* W_hh      = (const float*)d_in[13];
    const float* b_ih      = (const float*)d_in[14];
    const float* b_hh      = (const float*)d_in[15];
    const float* mlp_w1    = (const float*)d_in[16];
    const float* mlp_b1    = (const float*)d_in[17];
    const float* mlp_w2    = (const float*)d_in[18];
    const float* mlp_b2    = (const float*)d_in[19];
    const float* sbg_mu    = (const float*)d_in[20];
    const float* sbg_ls    = (const float*)d_in[21];
    const float* s_mu      = (const float*)d_in[22];
    const float* s_ls      = (const float*)d_in[23];

    char* ws = (char*)d_ws;
    size_t off = 0;
    auto alloc = [&](size_t bytes) {
        void* p = ws + off;
        off += (bytes + 255) & ~(size_t)255;
        return p;
    };
    ushortT* kg    = (ushortT*)alloc((size_t)BB * NN * 64 * 2);   // 64 MiB
    ushortT* vtg   = (ushortT*)alloc((size_t)BB * NN * 64 * 2);   // 64 MiB
    ushortT* Wkv   = (ushortT*)alloc(8192 * 2);
    float* slots   = (float*)alloc(57344 * 4);
    float* qbuf    = (float*)alloc(57344 * 4);
    float* num_p   = (float*)alloc((size_t)4096 * 7 * 64 * 4);    // 7.34 MB
    float* den_p   = (float*)alloc(4096 * 8 * 4);
    float* WihT    = (float*)alloc(12288 * 4);
    float* WhhT    = (float*)alloc(12288 * 4);
    float* w1T     = (float*)alloc(8192 * 4);
    float* w2T     = (float*)alloc(8192 * 4);
    if (off > ws_size) return;

    prep_w<<<192, 256, 0, stream>>>(Wk, Wv, W_ih, W_hh, mlp_w1, mlp_w2,
                                    Wkv, WihT, WhhT, w1T, w2T);
    prep_slots<<<224, 256, 0, stream>>>(noise_bg, noise_fg, sbg_mu, sbg_ls,
                                        s_mu, s_ls, slots);
    kv_proj<<<8192, 256, 0, stream>>>(inputs, ln_in_g, ln_in_b, Wkv, kg, vtg);
    for (int it = 0; it < N_ITERS; ++it) {
        slots_q<<<128, 448, 0, stream>>>(slots, Wq, ln_slot_g, ln_slot_b, qbuf);
        attn_kernel<<<4096, 256, 0, stream>>>(kg, vtg, qbuf, num_p, den_p);
        slot_update<<<896, 192, 0, stream>>>(num_p, den_p, slots, WihT, WhhT,
                                             b_ih, b_hh, ln_mlp_g, ln_mlp_b,
                                             w1T, mlp_b1, w2T, mlp_b2,
                                             (float*)d_out,
                                             (it == N_ITERS - 1) ? 1 : 0);
    }
}

// Round 4
// 399.446 us; speedup vs baseline: 3.9621x; 1.0748x over previous
//
#include <hip/hip_runtime.h>

// ---------------- problem constants ----------------
#define BB 128
#define NN 4096
#define DD 64
#define SS 7
#define HH 128
#define N_ITERS 3
#define EPS_ATTN 1e-8f
#define LN_EPS 1e-5f
// scale = D^-0.5 = 0.125 (folded into q)

typedef unsigned short ushortT;
using short8  = __attribute__((ext_vector_type(8))) short;
using floatx4 = __attribute__((ext_vector_type(4))) float;

__device__ __forceinline__ float bf2f(int u) {
    return __builtin_bit_cast(float, (unsigned)(u & 0xffff) << 16);
}
__device__ __forceinline__ ushortT f2bf(float f) {
    unsigned x = __builtin_bit_cast(unsigned, f);
    x = x + 0x7fff + ((x >> 16) & 1);   // RNE
    return (ushortT)(x >> 16);
}
__device__ __forceinline__ void wave_stats64(float x, float& mu, float& var) {
    float s1 = x, s2 = x * x;
#pragma unroll
    for (int off = 32; off > 0; off >>= 1) {
        s1 += __shfl_xor(s1, off);
        s2 += __shfl_xor(s2, off);
    }
    mu  = s1 * (1.f / 64.f);
    var = s2 * (1.f / 64.f) - mu * mu;
}

// ---------------- prep: pack weights ----------------
// Wkvf: frag-ordered bf16 table. idx = (tile*2+c)*512 + (qd*16+m)*8 + j holds
// W[tile*16+m][c*32+qd*8+j] (tiles 0..3 = Wk rows, 4..7 = Wv rows). kv_proj's
// fragment loads become lane-linear (1KB contiguous per instr).
__global__ void prep_w(const float* __restrict__ Wk, const float* __restrict__ Wv,
                       const float* __restrict__ Wih, const float* __restrict__ Whh,
                       const float* __restrict__ w1, const float* __restrict__ w2,
                       ushortT* __restrict__ Wkvf, float* __restrict__ WihT,
                       float* __restrict__ WhhT, float* __restrict__ w1T,
                       float* __restrict__ w2T) {
    int i = blockIdx.x * 256 + threadIdx.x;   // < 49152
    if (i < 8192) {
        int c2 = i >> 9, lane = (i >> 3) & 63, j = i & 7;
        int tile = c2 >> 1, cc = c2 & 1;
        int qd = lane >> 4, m = lane & 15;
        int row = tile * 16 + m;             // 0..127
        int col = cc * 32 + qd * 8 + j;
        float v = (row < 64) ? Wk[row * 64 + col] : Wv[(row - 64) * 64 + col];
        Wkvf[i] = f2bf(v);
    } else if (i < 20480) {
        int j = i - 8192; int e = j >> 6, d = j & 63;
        WihT[d * 192 + e] = Wih[j];
    } else if (i < 32768) {
        int j = i - 20480; int e = j >> 6, d = j & 63;
        WhhT[d * 192 + e] = Whh[j];
    } else if (i < 40960) {
        int j = i - 32768; int e = j >> 6, d = j & 63;   // w1 [128][64]
        w1T[d * 128 + e] = w1[j];
    } else if (i < 49152) {
        int j = i - 40960; int e = j >> 7, h = j & 127;  // w2 [64][128]
        w2T[h * 64 + e] = w2[j];
    }
}

// ---------------- fused LN + K/V projection (MFMA) ----------------
// 64 rows/block, grid 8192. All global access lane-linear:
//  kg  frag layout: idx = panel*4096 + w*1024 + tt*256 + (qd*16+m)*4 + j
//      element = k[panel*64 + w*16 + m][tt*16 + qd*4 + j]
//  vtg frag layout: idx = chunk*8192 + tt*2048 + ks*512 + (qd2*16+m)*8 + j
//      element = v[chunk*128 + ks*32 + qd2*8 + j][tt*16 + m]
__global__ __launch_bounds__(256) void kv_proj(const float* __restrict__ x,
                                               const float* __restrict__ g,
                                               const float* __restrict__ bta,
                                               const ushortT* __restrict__ Wkvf,
                                               ushortT* __restrict__ kg,
                                               ushortT* __restrict__ vtg) {
    int t = threadIdx.x, w = t >> 6, lane = t & 63;
    long row0 = (long)blockIdx.x << 6;
    int sub = t & 3, r = t >> 2;                    // 4 lanes per row, r in [0,64)
    __shared__ ushortT lds_a[64][72];               // 144B row stride

    // phase 1: LN, 16 dims per lane, coalesced float4 loads
    const float* xr = x + (row0 + r) * 64 + sub * 16;
    float4 xa[4];
#pragma unroll
    for (int c = 0; c < 4; ++c) xa[c] = *reinterpret_cast<const float4*>(xr + c * 4);
    float s1 = 0.f, s2 = 0.f;
#pragma unroll
    for (int c = 0; c < 4; ++c) {
        s1 += xa[c].x + xa[c].y + xa[c].z + xa[c].w;
        s2 += xa[c].x * xa[c].x + xa[c].y * xa[c].y +
              xa[c].z * xa[c].z + xa[c].w * xa[c].w;
    }
    s1 += __shfl_xor(s1, 1); s2 += __shfl_xor(s2, 1);
    s1 += __shfl_xor(s1, 2); s2 += __shfl_xor(s2, 2);
    float mu = s1 * (1.f / 64.f);
    float var = s2 * (1.f / 64.f) - mu * mu;
    float rs = rsqrtf(var + LN_EPS);
    unsigned un[8];
#pragma unroll
    for (int c = 0; c < 4; ++c) {
        float4 g4 = *reinterpret_cast<const float4*>(g + sub * 16 + c * 4);
        float4 b4 = *reinterpret_cast<const float4*>(bta + sub * 16 + c * 4);
        float n0 = (xa[c].x - mu) * rs * g4.x + b4.x;
        float n1 = (xa[c].y - mu) * rs * g4.y + b4.y;
        float n2 = (xa[c].z - mu) * rs * g4.z + b4.z;
        float n3 = (xa[c].w - mu) * rs * g4.w + b4.w;
        un[c * 2]     = (unsigned)f2bf(n0) | ((unsigned)f2bf(n1) << 16);
        un[c * 2 + 1] = (unsigned)f2bf(n2) | ((unsigned)f2bf(n3) << 16);
    }
    *reinterpret_cast<uint4*>(&lds_a[r][sub * 16]) =
        make_uint4(un[0], un[1], un[2], un[3]);
    *reinterpret_cast<uint4*>(&lds_a[r][sub * 16 + 8]) =
        make_uint4(un[4], un[5], un[6], un[7]);

    int m = lane & 15, qd = lane >> 4;
    // k-half weight frags — lane-linear coalesced loads
    short8 bk[4][2];
#pragma unroll
    for (int tt = 0; tt < 4; ++tt)
#pragma unroll
        for (int c = 0; c < 2; ++c)
            bk[tt][c] = *reinterpret_cast<const short8*>(
                Wkvf + (tt * 2 + c) * 512 + lane * 8);
    __syncthreads();

    short8 af[2];
#pragma unroll
    for (int c = 0; c < 2; ++c)
        af[c] = *reinterpret_cast<const short8*>(&lds_a[w * 16 + m][c * 32 + qd * 8]);

    // k-half: swapped operands -> lane holds k[w*16+m][tt*16+qd*4 .. +4]
    floatx4 ak[4];
#pragma unroll
    for (int tt = 0; tt < 4; ++tt) ak[tt] = (floatx4){0.f, 0.f, 0.f, 0.f};
#pragma unroll
    for (int tt = 0; tt < 4; ++tt)
#pragma unroll
        for (int c = 0; c < 2; ++c)
            ak[tt] = __builtin_amdgcn_mfma_f32_16x16x32_bf16(bk[tt][c], af[c],
                                                             ak[tt], 0, 0, 0);
    // k stores: 4 x 8B at lane*8 bytes — 512B contiguous per instr
    long kbase = ((long)blockIdx.x << 12) + w * 1024 + lane * 4;
#pragma unroll
    for (int tt = 0; tt < 4; ++tt) {
        uint2 u;
        u.x = (unsigned)f2bf(ak[tt][0]) | ((unsigned)f2bf(ak[tt][1]) << 16);
        u.y = (unsigned)f2bf(ak[tt][2]) | ((unsigned)f2bf(ak[tt][3]) << 16);
        *reinterpret_cast<uint2*>(kg + kbase + tt * 256) = u;
    }

    // v-half: normal orientation -> lane holds v[row0+w*16+qd*4+j][tt*16+m]
    short8 bv[4][2];
#pragma unroll
    for (int tt = 0; tt < 4; ++tt)
#pragma unroll
        for (int c = 0; c < 2; ++c)
            bv[tt][c] = *reinterpret_cast<const short8*>(
                Wkvf + ((tt + 4) * 2 + c) * 512 + lane * 8);
    floatx4 av[4];
#pragma unroll
    for (int tt = 0; tt < 4; ++tt) av[tt] = (floatx4){0.f, 0.f, 0.f, 0.f};
#pragma unroll
    for (int tt = 0; tt < 4; ++tt)
#pragma unroll
        for (int c = 0; c < 2; ++c)
            av[tt] = __builtin_amdgcn_mfma_f32_16x16x32_bf16(af[c], bv[tt][c],
                                                             av[tt], 0, 0, 0);
    // v stores: rl = (row0&127) + w*16 + qd*4 + j
    int ks  = (((int)(row0 & 127)) + w * 16) >> 5;
    int qd2 = (w * 2 + (qd >> 1)) & 3;
    long vbase = (((long)blockIdx.x >> 1) << 13) + ks * 512 + qd2 * 128 + m * 8 +
                 (qd & 1) * 4;
#pragma unroll
    for (int tt = 0; tt < 4; ++tt) {
        uint2 u;
        u.x = (unsigned)f2bf(av[tt][0]) | ((unsigned)f2bf(av[tt][1]) << 16);
        u.y = (unsigned)f2bf(av[tt][2]) | ((unsigned)f2bf(av[tt][3]) << 16);
        *reinterpret_cast<uint2*>(vtg + vbase + tt * 2048) = u;
    }
}

// ---------------- per-iter: attention (frag-ordered k/v, no atomics) -------
__global__ __launch_bounds__(256) void attn_kernel(const ushortT* __restrict__ kg,
                                                   const ushortT* __restrict__ vtg,
                                                   const float* __restrict__ qbuf,
                                                   float* __restrict__ num_p,
                                                   float* __restrict__ den_p) {
    int t = threadIdx.x;
    int ck = blockIdx.x;                 // 128-row chunk; b = ck>>5
    int b = ck >> 5;
    __shared__ float   q_lds[7][68];
    __shared__ ushortT p_lds[16][136];
    __shared__ float   den_w[4][8];
    int w = t >> 6, lane = t & 63, m = lane & 15, qd = lane >> 4;
    int sub = t & 3, rr = t >> 2;        // rr = w*16 + (lane>>2)

    // prefetch k: frag layout, 4 full lines per instr
    uint2 kf[2][4];
#pragma unroll
    for (int p = 0; p < 2; ++p) {
        const ushortT* kp = kg + ((long)(ck * 2 + p) << 12) + w * 1024 +
                            sub * 256 + (lane >> 2) * 4;
#pragma unroll
        for (int dq = 0; dq < 4; ++dq)
            kf[p][dq] = *reinterpret_cast<const uint2*>(kp + dq * 64);
    }
    // prefetch v B-frags: perfectly coalesced 1KB per instr
    const ushortT* vb = vtg + ((long)ck << 13) + w * 2048 + lane * 8;
    short8 bf[4];
#pragma unroll
    for (int ks = 0; ks < 4; ++ks)
        bf[ks] = *reinterpret_cast<const short8*>(vb + ks * 512);
    for (int i = t; i < 448; i += 256) q_lds[i >> 6][i & 63] = qbuf[b * 448 + i];
    __syncthreads();

    float dreg0 = 0.f, dreg1 = 0.f;
    int s0 = sub * 2;
#pragma unroll
    for (int p = 0; p < 2; ++p) {
        int row = p * 64 + rr;
        float kx[16];
#pragma unroll
        for (int dq = 0; dq < 4; ++dq) {
            kx[dq * 4 + 0] = bf2f(kf[p][dq].x);
            kx[dq * 4 + 1] = bf2f(kf[p][dq].x >> 16);
            kx[dq * 4 + 2] = bf2f(kf[p][dq].y);
            kx[dq * 4 + 3] = bf2f(kf[p][dq].y >> 16);
        }
        float lg[7];
#pragma unroll
        for (int s = 0; s < 7; ++s) {
            const float4* qp = reinterpret_cast<const float4*>(&q_lds[s][sub << 4]);
            float acc = 0.f;
#pragma unroll
            for (int c = 0; c < 4; ++c) {
                float4 qv = qp[c];
                acc += kx[c * 4 + 0] * qv.x + kx[c * 4 + 1] * qv.y +
                       kx[c * 4 + 2] * qv.z + kx[c * 4 + 3] * qv.w;
            }
            lg[s] = acc;
        }
#pragma unroll
        for (int s = 0; s < 7; ++s) {
            lg[s] += __shfl_xor(lg[s], 1);
            lg[s] += __shfl_xor(lg[s], 2);
        }
        float mx = lg[0];
#pragma unroll
        for (int s = 1; s < 7; ++s) mx = fmaxf(mx, lg[s]);
        float sum = 0.f, ps[7];
#pragma unroll
        for (int s = 0; s < 7; ++s) { ps[s] = __expf(lg[s] - mx); sum += ps[s]; }
        float inv = 1.f / sum;
        float p0 = 0.f, p1 = 0.f;
#pragma unroll
        for (int s = 0; s < 7; ++s) {
            float pv = ps[s] * inv + EPS_ATTN;
            if (s == s0)     p0 = pv;
            if (s == s0 + 1) p1 = pv;
        }
        ushortT pb0 = f2bf(p0);
        p_lds[s0][row] = pb0;
        dreg0 += bf2f(pb0);
        if (sub < 3) {
            ushortT pb1 = f2bf(p1);
            p_lds[s0 + 1][row] = pb1;
            dreg1 += bf2f(pb1);
        }
    }
#pragma unroll
    for (int off = 4; off < 64; off <<= 1) {
        dreg0 += __shfl_xor(dreg0, off);
        dreg1 += __shfl_xor(dreg1, off);
    }
    if (lane < 4) {
        den_w[w][2 * lane] = dreg0;
        if (lane < 3) den_w[w][2 * lane + 1] = dreg1;
    }
    __syncthreads();

    floatx4 acc = (floatx4){0.f, 0.f, 0.f, 0.f};
#pragma unroll
    for (int ks = 0; ks < 4; ++ks) {
        short8 af = *reinterpret_cast<const short8*>(&p_lds[m][ks * 32 + qd * 8]);
        acc = __builtin_amdgcn_mfma_f32_16x16x32_bf16(af, bf[ks], acc, 0, 0, 0);
    }
#pragma unroll
    for (int r = 0; r < 4; ++r) {
        int s = qd * 4 + r;
        if (s < 7) num_p[((long)ck * 7 + s) * 64 + w * 16 + m] = acc[r];
    }
    if (t < 7) den_p[ck * 8 + t] = den_w[0][t] + den_w[1][t] + den_w[2][t] + den_w[3][t];
}

// ---------------- fused slots pipeline: [reduce+GRU+LN+MLP] + [LN+q] -------
// 448 threads = 7 waves; wave s owns slot s of batch b = blockIdx.x.
// mode 0: init slots from noise, then LN+q.  mode 1: full update, then LN+q.
// mode 2: full update, write output, no q.
__global__ __launch_bounds__(448) void slot_update_q(
    int mode,
    const float* __restrict__ num_p, const float* __restrict__ den_p,
    float* __restrict__ slots,
    const float* __restrict__ nbg, const float* __restrict__ nfg,
    const float* __restrict__ bgmu, const float* __restrict__ bgls,
    const float* __restrict__ fmu, const float* __restrict__ fls,
    const float* __restrict__ WihT, const float* __restrict__ WhhT,
    const float* __restrict__ bih, const float* __restrict__ bhh,
    const float* __restrict__ lng, const float* __restrict__ lnb,
    const float* __restrict__ w1T, const float* __restrict__ b1,
    const float* __restrict__ w2T, const float* __restrict__ b2,
    const float* __restrict__ Wq,
    const float* __restrict__ sg, const float* __restrict__ sb,
    float* __restrict__ qbuf, float* __restrict__ outp) {
    int b = blockIdx.x, t = threadIdx.x, s = t >> 6, l = t & 63;
    __shared__ float WqT[64 * 65];
    __shared__ float updL[7][64], hprevL[7][64], mnL[7][64], m1L[7][128], xnL[7][64];
    if (mode != 2)
        for (int i = t; i < 4096; i += 448)
            WqT[(i & 63) * 65 + (i >> 6)] = Wq[i];
    float res;
    if (mode == 0) {
        float v;
        if (s == 0) v = bgmu[l] + __expf(bgls[l]) * nbg[b * 64 + l];
        else        v = fmu[l]  + __expf(fls[l])  * nfg[(b * 6 + s - 1) * 64 + l];
        res = v;
        __syncthreads();                 // WqT ready
    } else {
        float nsum = 0.f, dsum = 0.f;
#pragma unroll 4
        for (int c = 0; c < 32; ++c) {
            nsum += num_p[((long)(b * 32 + c) * 7 + s) * 64 + l];
            dsum += den_p[(b * 32 + c) * 8 + s];
        }
        float hp = slots[(b * 7 + s) * 64 + l];
        updL[s][l]   = nsum / dsum;
        hprevL[s][l] = hp;
        __syncthreads();                 // WqT ready (updL/hprevL wave-private)
        float gi0 = bih[l], gi1 = bih[64 + l], gi2 = bih[128 + l];
        float gh0 = bhh[l], gh1 = bhh[64 + l], gh2 = bhh[128 + l];
#pragma unroll 8
        for (int d = 0; d < 64; ++d) {
            float u = updL[s][d], hh = hprevL[s][d];
            gi0 += u * WihT[d * 192 + l];
            gi1 += u * WihT[d * 192 + 64 + l];
            gi2 += u * WihT[d * 192 + 128 + l];
            gh0 += hh * WhhT[d * 192 + l];
            gh1 += hh * WhhT[d * 192 + 64 + l];
            gh2 += hh * WhhT[d * 192 + 128 + l];
        }
        float r = 1.f / (1.f + __expf(-(gi0 + gh0)));
        float z = 1.f / (1.f + __expf(-(gi1 + gh1)));
        float n = tanhf(gi2 + r * gh2);
        float h = (1.f - z) * n + z * hp;
        float mu, var;
        wave_stats64(h, mu, var);
        mnL[s][l] = (h - mu) * rsqrtf(var + LN_EPS) * lng[l] + lnb[l];
        float a0 = b1[l], a1 = b1[64 + l];
#pragma unroll 8
        for (int d = 0; d < 64; ++d) {
            float mv = mnL[s][d];
            a0 += mv * w1T[d * 128 + l];
            a1 += mv * w1T[d * 128 + 64 + l];
        }
        m1L[s][l]      = fmaxf(a0, 0.f);
        m1L[s][64 + l] = fmaxf(a1, 0.f);
        float a2 = b2[l];
#pragma unroll 8
        for (int h2 = 0; h2 < 128; ++h2) a2 += m1L[s][h2] * w2T[h2 * 64 + l];
        res = h + a2;
    }
    slots[(b * 7 + s) * 64 + l] = res;
    if (mode == 2) {
        outp[(b * 7 + s) * 64 + l] = res;
        return;
    }
    // slot LN + q projection (folds D^-0.5)
    float mu, var;
    wave_stats64(res, mu, var);
    xnL[s][l] = (res - mu) * rsqrtf(var + LN_EPS) * sg[l] + sb[l];
    float acc = 0.f;
#pragma unroll 8
    for (int d = 0; d < 64; ++d) acc += xnL[s][d] * WqT[d * 65 + l];
    qbuf[(b * 7 + s) * 64 + l] = acc * 0.125f;
}

// ---------------- launcher ----------------
extern "C" void kernel_launch(void* const* d_in, const int* in_sizes, int n_in,
                              void* d_out, int out_size, void* d_ws, size_t ws_size,
                              hipStream_t stream) {
    const float* inputs    = (const float*)d_in[0];
    const float* noise_bg  = (const float*)d_in[1];
    const float* noise_fg  = (const float*)d_in[2];
    const float* ln_in_g   = (const float*)d_in[3];
    const float* ln_in_b   = (const float*)d_in[4];
    const float* ln_slot_g = (const float*)d_in[5];
    const float* ln_slot_b = (const float*)d_in[6];
    const float* ln_mlp_g  = (const float*)d_in[7];
    const float* ln_mlp_b  = (const float*)d_in[8];
    const float* Wq        = (const float*)d_in[9];
    const float* Wk        = (const float*)d_in[10];
    const float* Wv        = (const float*)d_in[11];
    const float* W_ih      = (const float*)d_in[12];
    const float* W_hh      = (const float*)d_in[13];
    const float* b_ih      = (const float*)d_in[14];
    const float* b_hh      = (const float*)d_in[15];
    const float* mlp_w1    = (const float*)d_in[16];
    const float* mlp_b1    = (const float*)d_in[17];
    const float* mlp_w2    = (const float*)d_in[18];
    const float* mlp_b2    = (const float*)d_in[19];
    const float* sbg_mu    = (const float*)d_in[20];
    const float* sbg_ls    = (const float*)d_in[21];
    const float* s_mu      = (const float*)d_in[22];
    const float* s_ls      = (const float*)d_in[23];

    char* ws = (char*)d_ws;
    size_t off = 0;
    auto alloc = [&](size_t bytes) {
        void* p = ws + off;
        off += (bytes + 255) & ~(size_t)255;
        return p;
    };
    ushortT* kg    = (ushortT*)alloc((size_t)BB * NN * 64 * 2);   // 64 MiB
    ushortT* vtg   = (ushortT*)alloc((size_t)BB * NN * 64 * 2);   // 64 MiB
    ushortT* Wkvf  = (ushortT*)alloc(8192 * 2);
    float* slots   = (float*)alloc(57344 * 4);
    float* qbuf    = (float*)alloc(57344 * 4);
    float* num_p   = (float*)alloc((size_t)4096 * 7 * 64 * 4);    // 7.34 MB
    float* den_p   = (float*)alloc(4096 * 8 * 4);
    float* WihT    = (float*)alloc(12288 * 4);
    float* WhhT    = (float*)alloc(12288 * 4);
    float* w1T     = (float*)alloc(8192 * 4);
    float* w2T     = (float*)alloc(8192 * 4);
    if (off > ws_size) return;

    prep_w<<<192, 256, 0, stream>>>(Wk, Wv, W_ih, W_hh, mlp_w1, mlp_w2,
                                    Wkvf, WihT, WhhT, w1T, w2T);
    slot_update_q<<<128, 448, 0, stream>>>(0, num_p, den_p, slots,
                                           noise_bg, noise_fg, sbg_mu, sbg_ls,
                                           s_mu, s_ls, WihT, WhhT, b_ih, b_hh,
                                           ln_mlp_g, ln_mlp_b, w1T, mlp_b1,
                                           w2T, mlp_b2, Wq, ln_slot_g, ln_slot_b,
                                           qbuf, (float*)d_out);
    kv_proj<<<8192, 256, 0, stream>>>(inputs, ln_in_g, ln_in_b, Wkvf, kg, vtg);
    for (int it = 0; it < N_ITERS; ++it) {
        attn_kernel<<<4096, 256, 0, stream>>>(kg, vtg, qbuf, num_p, den_p);
        slot_update_q<<<128, 448, 0, stream>>>((it == N_ITERS - 1) ? 2 : 1,
                                               num_p, den_p, slots,
                                               noise_bg, noise_fg, sbg_mu, sbg_ls,
                                               s_mu, s_ls, WihT, WhhT, b_ih, b_hh,
                                               ln_mlp_g, ln_mlp_b, w1T, mlp_b1,
                                               w2T, mlp_b2, Wq, ln_slot_g, ln_slot_b,
                                               qbuf, (float*)d_out);
    }
}

// Round 5
// 382.616 us; speedup vs baseline: 4.1364x; 1.0440x over previous
//
#include <hip/hip_runtime.h>

// ---------------- problem constants ----------------
#define BB 128
#define NN 4096
#define DD 64
#define SS 7
#define HH 128
#define N_ITERS 3
#define EPS_ATTN 1e-8f
#define LN_EPS 1e-5f
// scale = D^-0.5 = 0.125 (folded into q, propagates linearly into qk)

typedef unsigned short ushortT;
using short8  = __attribute__((ext_vector_type(8))) short;
using floatx4 = __attribute__((ext_vector_type(4))) float;

__device__ __forceinline__ float bf2f(unsigned u) {
    return __builtin_bit_cast(float, (u & 0xffffu) << 16);
}
__device__ __forceinline__ ushortT f2bf(float f) {
    unsigned x = __builtin_bit_cast(unsigned, f);
    x = x + 0x7fff + ((x >> 16) & 1);   // RNE
    return (ushortT)(x >> 16);
}
__device__ __forceinline__ void wave_stats64(float x, float& mu, float& var) {
    float s1 = x, s2 = x * x;
#pragma unroll
    for (int off = 32; off > 0; off >>= 1) {
        s1 += __shfl_xor(s1, off);
        s2 += __shfl_xor(s2, off);
    }
    mu  = s1 * (1.f / 64.f);
    var = s2 * (1.f / 64.f) - mu * mu;
}

// ---------------- prep: pack/transpose small weights ----------------
// WihT/WhhT [64][192], w1T [64][128], w2T [128][64], WvT [64 e][64 d].
__global__ void prep_w(const float* __restrict__ Wih, const float* __restrict__ Whh,
                       const float* __restrict__ w1, const float* __restrict__ w2,
                       const float* __restrict__ Wv,
                       float* __restrict__ WihT, float* __restrict__ WhhT,
                       float* __restrict__ w1T, float* __restrict__ w2T,
                       float* __restrict__ WvT) {
    int i = blockIdx.x * 256 + threadIdx.x;   // < 45056
    if (i < 12288) {
        int e = i >> 6, d = i & 63;
        WihT[d * 192 + e] = Wih[i];
    } else if (i < 24576) {
        int j = i - 12288; int e = j >> 6, d = j & 63;
        WhhT[d * 192 + e] = Whh[j];
    } else if (i < 32768) {
        int j = i - 24576; int e = j >> 6, d = j & 63;   // w1 [128][64]
        w1T[d * 128 + e] = w1[j];
    } else if (i < 40960) {
        int j = i - 32768; int e = j >> 7, h = j & 127;  // w2 [64][128]
        w2T[h * 64 + e] = w2[j];
    } else if (i < 45056) {
        int j = i - 40960; int d = j >> 6, e = j & 63;   // Wv [d][e] -> WvT [e][d]
        WvT[e * 64 + d] = Wv[j];
    }
}

// ---------------- per-iter: attention on xn only ----------------
// One block = one 128-row chunk (grid 4096; b = ck>>5).
// first=1: load x fp32, LN -> xn bf16 regs, store xnf (lane-private layout:
//   xnf[ck*8192 + pass*4096 + t*16 + {0..15}] = dims of row pass*64+(t>>2),
//   dim range (t&3)*16..+16) — 2KB fully-contiguous per wave-store.
// first=0: reload the same 32B per lane.
// Phase 1: logits[row][s] = xn[row]·qk[s] (4 lanes/row, shfl-reduce), softmax,
//   p -> p_lds bf16; xn -> xnT LDS (transposed) for the P·XN MFMA.
// Phase 2: MFMA pxn[s][e] = P^T(16x128) x XN(128x64); store pxn/den partials.
__global__ __launch_bounds__(256) void attn_kernel(
    int first,
    const float* __restrict__ x,
    const float* __restrict__ lng, const float* __restrict__ lnb,
    ushortT* __restrict__ xnf,
    const float* __restrict__ qkbuf,
    float* __restrict__ pxn_p, float* __restrict__ den_p) {
    int t = threadIdx.x;
    int ck = blockIdx.x, b = ck >> 5;
    int w = t >> 6, lane = t & 63, m = lane & 15, qd = lane >> 4;
    int sub = t & 3, rr = t >> 2;            // rr in [0,64): block-row within pass
    __shared__ float   qk_lds[7][68];
    __shared__ ushortT xnT[64][136];         // [e][row], 272B row stride
    __shared__ ushortT p_lds[16][136];       // rows 7..15 garbage (discarded)
    __shared__ float   den_w[4][8];

    unsigned xw[2][8];                       // per pass: 16 bf16 dims packed
    if (first) {
        float4 g4[4], b4[4];
#pragma unroll
        for (int c = 0; c < 4; ++c) {
            g4[c] = *reinterpret_cast<const float4*>(lng + sub * 16 + c * 4);
            b4[c] = *reinterpret_cast<const float4*>(lnb + sub * 16 + c * 4);
        }
#pragma unroll
        for (int pass = 0; pass < 2; ++pass) {
            const float* xr = x + ((long)ck * 128 + pass * 64 + rr) * 64 + sub * 16;
            float4 xa[4];
#pragma unroll
            for (int c = 0; c < 4; ++c)
                xa[c] = *reinterpret_cast<const float4*>(xr + c * 4);
            float s1 = 0.f, s2 = 0.f;
#pragma unroll
            for (int c = 0; c < 4; ++c) {
                s1 += xa[c].x + xa[c].y + xa[c].z + xa[c].w;
                s2 += xa[c].x * xa[c].x + xa[c].y * xa[c].y +
                      xa[c].z * xa[c].z + xa[c].w * xa[c].w;
            }
            s1 += __shfl_xor(s1, 1); s2 += __shfl_xor(s2, 1);
            s1 += __shfl_xor(s1, 2); s2 += __shfl_xor(s2, 2);
            float mu = s1 * (1.f / 64.f);
            float var = s2 * (1.f / 64.f) - mu * mu;
            float rs = rsqrtf(var + LN_EPS);
#pragma unroll
            for (int c = 0; c < 4; ++c) {
                float n0 = (xa[c].x - mu) * rs * g4[c].x + b4[c].x;
                float n1 = (xa[c].y - mu) * rs * g4[c].y + b4[c].y;
                float n2 = (xa[c].z - mu) * rs * g4[c].z + b4[c].z;
                float n3 = (xa[c].w - mu) * rs * g4[c].w + b4[c].w;
                xw[pass][c * 2]     = (unsigned)f2bf(n0) | ((unsigned)f2bf(n1) << 16);
                xw[pass][c * 2 + 1] = (unsigned)f2bf(n2) | ((unsigned)f2bf(n3) << 16);
            }
            ushortT* xp = xnf + (long)ck * 8192 + pass * 4096 + t * 16;
            *reinterpret_cast<uint4*>(xp) =
                make_uint4(xw[pass][0], xw[pass][1], xw[pass][2], xw[pass][3]);
            *reinterpret_cast<uint4*>(xp + 8) =
                make_uint4(xw[pass][4], xw[pass][5], xw[pass][6], xw[pass][7]);
        }
    } else {
#pragma unroll
        for (int pass = 0; pass < 2; ++pass) {
            const ushortT* xp = xnf + (long)ck * 8192 + pass * 4096 + t * 16;
            uint4 u0 = *reinterpret_cast<const uint4*>(xp);
            uint4 u1 = *reinterpret_cast<const uint4*>(xp + 8);
            xw[pass][0] = u0.x; xw[pass][1] = u0.y;
            xw[pass][2] = u0.z; xw[pass][3] = u0.w;
            xw[pass][4] = u1.x; xw[pass][5] = u1.y;
            xw[pass][6] = u1.z; xw[pass][7] = u1.w;
        }
    }
    for (int i = t; i < 448; i += 256) qk_lds[i >> 6][i & 63] = qkbuf[b * 448 + i];
    __syncthreads();

    float dreg0 = 0.f, dreg1 = 0.f;
    int s0 = sub * 2;
#pragma unroll
    for (int pass = 0; pass < 2; ++pass) {
        int row = pass * 64 + rr;
        // stash xn into transposed LDS for phase 2
#pragma unroll
        for (int j = 0; j < 16; ++j)
            xnT[sub * 16 + j][row] =
                (ushortT)(xw[pass][j >> 1] >> ((j & 1) * 16));
        float kx[16];
#pragma unroll
        for (int j = 0; j < 8; ++j) {
            kx[2 * j]     = bf2f(xw[pass][j]);
            kx[2 * j + 1] = bf2f(xw[pass][j] >> 16);
        }
        float lg[7];
#pragma unroll
        for (int s = 0; s < 7; ++s) {
            const float4* qp = reinterpret_cast<const float4*>(&qk_lds[s][sub << 4]);
            float acc = 0.f;
#pragma unroll
            for (int c = 0; c < 4; ++c) {
                float4 qv = qp[c];
                acc += kx[c * 4 + 0] * qv.x + kx[c * 4 + 1] * qv.y +
                       kx[c * 4 + 2] * qv.z + kx[c * 4 + 3] * qv.w;
            }
            lg[s] = acc;
        }
#pragma unroll
        for (int s = 0; s < 7; ++s) {
            lg[s] += __shfl_xor(lg[s], 1);
            lg[s] += __shfl_xor(lg[s], 2);
        }
        float mx = lg[0];
#pragma unroll
        for (int s = 1; s < 7; ++s) mx = fmaxf(mx, lg[s]);
        float sum = 0.f, ps[7];
#pragma unroll
        for (int s = 0; s < 7; ++s) { ps[s] = __expf(lg[s] - mx); sum += ps[s]; }
        float inv = 1.f / sum;
        float p0 = 0.f, p1 = 0.f;
#pragma unroll
        for (int s = 0; s < 7; ++s) {
            float pv = ps[s] * inv + EPS_ATTN;
            if (s == s0)     p0 = pv;
            if (s == s0 + 1) p1 = pv;
        }
        ushortT pb0 = f2bf(p0);
        p_lds[s0][row] = pb0;
        dreg0 += bf2f(pb0);
        if (sub < 3) {
            ushortT pb1 = f2bf(p1);
            p_lds[s0 + 1][row] = pb1;
            dreg1 += bf2f(pb1);
        }
    }
#pragma unroll
    for (int off = 4; off < 64; off <<= 1) {
        dreg0 += __shfl_xor(dreg0, off);
        dreg1 += __shfl_xor(dreg1, off);
    }
    if (lane < 4) {
        den_w[w][2 * lane] = dreg0;
        if (lane < 3) den_w[w][2 * lane + 1] = dreg1;
    }
    __syncthreads();

    // phase 2: pxn[s][e] — wave w owns e-tile w*16..+16
    floatx4 acc = (floatx4){0.f, 0.f, 0.f, 0.f};
#pragma unroll
    for (int ks = 0; ks < 4; ++ks) {
        short8 af = *reinterpret_cast<const short8*>(&p_lds[m][ks * 32 + qd * 8]);
        short8 bf = *reinterpret_cast<const short8*>(&xnT[w * 16 + m][ks * 32 + qd * 8]);
        acc = __builtin_amdgcn_mfma_f32_16x16x32_bf16(af, bf, acc, 0, 0, 0);
    }
#pragma unroll
    for (int r = 0; r < 4; ++r) {
        int s = qd * 4 + r;
        if (s < 7) pxn_p[((long)ck * 7 + s) * 64 + w * 16 + m] = acc[r];
    }
    if (t < 7) den_p[ck * 8 + t] = den_w[0][t] + den_w[1][t] + den_w[2][t] + den_w[3][t];
}

// ---------------- fused slots pipeline ----------------
// 448 thr = 7 waves; wave s owns slot s of batch b.
// mode 0: init slots; mode 1: pxn->num (via WvT), GRU, LN, MLP; mode 2: same +
// write output. Modes 0/1 then do slot-LN + q (WqT) + qk = Wk^T q.
__global__ __launch_bounds__(448) void slot_update_q(
    int mode,
    const float* __restrict__ pxn_p, const float* __restrict__ den_p,
    float* __restrict__ slots,
    const float* __restrict__ nbg, const float* __restrict__ nfg,
    const float* __restrict__ bgmu, const float* __restrict__ bgls,
    const float* __restrict__ fmu, const float* __restrict__ fls,
    const float* __restrict__ WihT, const float* __restrict__ WhhT,
    const float* __restrict__ bih, const float* __restrict__ bhh,
    const float* __restrict__ lng, const float* __restrict__ lnb,
    const float* __restrict__ w1T, const float* __restrict__ b1,
    const float* __restrict__ w2T, const float* __restrict__ b2,
    const float* __restrict__ WvT, const float* __restrict__ Wk,
    const float* __restrict__ Wq,
    const float* __restrict__ sg, const float* __restrict__ sb,
    float* __restrict__ qkbuf, float* __restrict__ outp) {
    int b = blockIdx.x, t = threadIdx.x, s = t >> 6, l = t & 63;
    __shared__ float WqT[64 * 65];
    __shared__ float pxnL[7][64], updL[7][64], hprevL[7][64], mnL[7][64],
                     xnL[7][64], qL[7][64], m1L[7][128];
    if (mode != 2)
        for (int i = t; i < 4096; i += 448)
            WqT[(i & 63) * 65 + (i >> 6)] = Wq[i];
    float res;
    if (mode == 0) {
        float v;
        if (s == 0) v = bgmu[l] + __expf(bgls[l]) * nbg[b * 64 + l];
        else        v = fmu[l]  + __expf(fls[l])  * nfg[(b * 6 + s - 1) * 64 + l];
        res = v;
        __syncthreads();                 // WqT ready
    } else {
        float psum = 0.f, dsum = 0.f;
#pragma unroll 4
        for (int c = 0; c < 32; ++c) {
            psum += pxn_p[((long)(b * 32 + c) * 7 + s) * 64 + l];
            dsum += den_p[(b * 32 + c) * 8 + s];
        }
        pxnL[s][l] = psum;               // wave-private row
        float hp = slots[(b * 7 + s) * 64 + l];
        hprevL[s][l] = hp;
        // num[d=l] = sum_e pxn[e] * Wv[l][e] = sum_e pxnL[s][e]*WvT[e*64+l]
        float nm = 0.f;
#pragma unroll 8
        for (int e = 0; e < 64; ++e) nm += pxnL[s][e] * WvT[e * 64 + l];
        updL[s][l] = nm / dsum;
        __syncthreads();                 // WqT ready
        float gi0 = bih[l], gi1 = bih[64 + l], gi2 = bih[128 + l];
        float gh0 = bhh[l], gh1 = bhh[64 + l], gh2 = bhh[128 + l];
#pragma unroll 8
        for (int d = 0; d < 64; ++d) {
            float u = updL[s][d], hh = hprevL[s][d];
            gi0 += u * WihT[d * 192 + l];
            gi1 += u * WihT[d * 192 + 64 + l];
            gi2 += u * WihT[d * 192 + 128 + l];
            gh0 += hh * WhhT[d * 192 + l];
            gh1 += hh * WhhT[d * 192 + 64 + l];
            gh2 += hh * WhhT[d * 192 + 128 + l];
        }
        float r = 1.f / (1.f + __expf(-(gi0 + gh0)));
        float z = 1.f / (1.f + __expf(-(gi1 + gh1)));
        float n = tanhf(gi2 + r * gh2);
        float h = (1.f - z) * n + z * hp;
        float mu, var;
        wave_stats64(h, mu, var);
        mnL[s][l] = (h - mu) * rsqrtf(var + LN_EPS) * lng[l] + lnb[l];
        float a0 = b1[l], a1 = b1[64 + l];
#pragma unroll 8
        for (int d = 0; d < 64; ++d) {
            float mv = mnL[s][d];
            a0 += mv * w1T[d * 128 + l];
            a1 += mv * w1T[d * 128 + 64 + l];
        }
        m1L[s][l]      = fmaxf(a0, 0.f);
        m1L[s][64 + l] = fmaxf(a1, 0.f);
        float a2 = b2[l];
#pragma unroll 8
        for (int h2 = 0; h2 < 128; ++h2) a2 += m1L[s][h2] * w2T[h2 * 64 + l];
        res = h + a2;
    }
    slots[(b * 7 + s) * 64 + l] = res;
    if (mode == 2) {
        outp[(b * 7 + s) * 64 + l] = res;
        return;
    }
    // slot LN -> q (scale folded) -> qk = Wk^T q
    float mu, var;
    wave_stats64(res, mu, var);
    xnL[s][l] = (res - mu) * rsqrtf(var + LN_EPS) * sg[l] + sb[l];
    float qv = 0.f;
#pragma unroll 8
    for (int d = 0; d < 64; ++d) qv += xnL[s][d] * WqT[d * 65 + l];
    qL[s][l] = qv * 0.125f;
    float qk = 0.f;
#pragma unroll 8
    for (int e = 0; e < 64; ++e) qk += qL[s][e] * Wk[e * 64 + l];
    qkbuf[(b * 7 + s) * 64 + l] = qk;
}

// ---------------- launcher ----------------
extern "C" void kernel_launch(void* const* d_in, const int* in_sizes, int n_in,
                              void* d_out, int out_size, void* d_ws, size_t ws_size,
                              hipStream_t stream) {
    const float* inputs    = (const float*)d_in[0];
    const float* noise_bg  = (const float*)d_in[1];
    const float* noise_fg  = (const float*)d_in[2];
    const float* ln_in_g   = (const float*)d_in[3];
    const float* ln_in_b   = (const float*)d_in[4];
    const float* ln_slot_g = (const float*)d_in[5];
    const float* ln_slot_b = (const float*)d_in[6];
    const float* ln_mlp_g  = (const float*)d_in[7];
    const float* ln_mlp_b  = (const float*)d_in[8];
    const float* Wq        = (const float*)d_in[9];
    const float* Wk        = (const float*)d_in[10];
    const float* Wv        = (const float*)d_in[11];
    const float* W_ih      = (const float*)d_in[12];
    const float* W_hh      = (const float*)d_in[13];
    const float* b_ih      = (const float*)d_in[14];
    const float* b_hh      = (const float*)d_in[15];
    const float* mlp_w1    = (const float*)d_in[16];
    const float* mlp_b1    = (const float*)d_in[17];
    const float* mlp_w2    = (const float*)d_in[18];
    const float* mlp_b2    = (const float*)d_in[19];
    const float* sbg_mu    = (const float*)d_in[20];
    const float* sbg_ls    = (const float*)d_in[21];
    const float* s_mu      = (const float*)d_in[22];
    const float* s_ls      = (const float*)d_in[23];

    char* ws = (char*)d_ws;
    size_t off = 0;
    auto alloc = [&](size_t bytes) {
        void* p = ws + off;
        off += (bytes + 255) & ~(size_t)255;
        return p;
    };
    ushortT* xnf   = (ushortT*)alloc((size_t)BB * NN * 64 * 2);   // 64 MiB bf16 xn
    float* slots   = (float*)alloc(57344 * 4);
    float* qkbuf   = (float*)alloc(57344 * 4);
    float* pxn_p   = (float*)alloc((size_t)4096 * 7 * 64 * 4);    // 7.34 MB
    float* den_p   = (float*)alloc(4096 * 8 * 4);
    float* WihT    = (float*)alloc(12288 * 4);
    float* WhhT    = (float*)alloc(12288 * 4);
    float* w1T     = (float*)alloc(8192 * 4);
    float* w2T     = (float*)alloc(8192 * 4);
    float* WvT     = (float*)alloc(4096 * 4);
    if (off > ws_size) return;

    prep_w<<<176, 256, 0, stream>>>(W_ih, W_hh, mlp_w1, mlp_w2, Wv,
                                    WihT, WhhT, w1T, w2T, WvT);
    slot_update_q<<<128, 448, 0, stream>>>(0, pxn_p, den_p, slots,
                                           noise_bg, noise_fg, sbg_mu, sbg_ls,
                                           s_mu, s_ls, WihT, WhhT, b_ih, b_hh,
                                           ln_mlp_g, ln_mlp_b, w1T, mlp_b1,
                                           w2T, mlp_b2, WvT, Wk, Wq,
                                           ln_slot_g, ln_slot_b,
                                           qkbuf, (float*)d_out);
    for (int it = 0; it < N_ITERS; ++it) {
        attn_kernel<<<4096, 256, 0, stream>>>((it == 0) ? 1 : 0,
                                              inputs, ln_in_g, ln_in_b,
                                              xnf, qkbuf, pxn_p, den_p);
        slot_update_q<<<128, 448, 0, stream>>>((it == N_ITERS - 1) ? 2 : 1,
                                               pxn_p, den_p, slots,
                                               noise_bg, noise_fg, sbg_mu, sbg_ls,
                                               s_mu, s_ls, WihT, WhhT, b_ih, b_hh,
                                               ln_mlp_g, ln_mlp_b, w1T, mlp_b1,
                                               w2T, mlp_b2, WvT, Wk, Wq,
                                               ln_slot_g, ln_slot_b,
                                               qkbuf, (float*)d_out);
    }
}

// Round 6
// 359.783 us; speedup vs baseline: 4.3989x; 1.0635x over previous
//
#include <hip/hip_runtime.h>

// ---------------- problem constants ----------------
#define BB 128
#define NN 4096
#define DD 64
#define SS 7
#define HH 128
#define N_ITERS 3
#define EPS_ATTN 1e-8f
#define LN_EPS 1e-5f
// scale = D^-0.5 = 0.125 (folded into q -> qk)

typedef unsigned short ushortT;
using short8  = __attribute__((ext_vector_type(8))) short;
using floatx4 = __attribute__((ext_vector_type(4))) float;
using uint4v  = __attribute__((ext_vector_type(4))) unsigned;

__device__ __forceinline__ float bf2f(unsigned u) {
    return __builtin_bit_cast(float, (u & 0xffffu) << 16);
}
__device__ __forceinline__ ushortT f2bf(float f) {
    unsigned x = __builtin_bit_cast(unsigned, f);
    x = x + 0x7fff + ((x >> 16) & 1);   // RNE
    return (ushortT)(x >> 16);
}
__device__ __forceinline__ void wave_stats64(float x, float& mu, float& var) {
    float s1 = x, s2 = x * x;
#pragma unroll
    for (int off = 32; off > 0; off >>= 1) {
        s1 += __shfl_xor(s1, off);
        s2 += __shfl_xor(s2, off);
    }
    mu  = s1 * (1.f / 64.f);
    var = s2 * (1.f / 64.f) - mu * mu;
}

// ---------------- prep: pack/transpose small weights ----------------
__global__ void prep_w(const float* __restrict__ Wih, const float* __restrict__ Whh,
                       const float* __restrict__ w1, const float* __restrict__ w2,
                       const float* __restrict__ Wv, const float* __restrict__ Wq,
                       float* __restrict__ WihT, float* __restrict__ WhhT,
                       float* __restrict__ w1T, float* __restrict__ w2T,
                       float* __restrict__ WvT, float* __restrict__ WqT) {
    int i = blockIdx.x * 256 + threadIdx.x;   // < 49152
    if (i < 12288) {
        int e = i >> 6, d = i & 63;
        WihT[d * 192 + e] = Wih[i];
    } else if (i < 24576) {
        int j = i - 12288; int e = j >> 6, d = j & 63;
        WhhT[d * 192 + e] = Whh[j];
    } else if (i < 32768) {
        int j = i - 24576; int e = j >> 6, d = j & 63;   // w1 [128][64]
        w1T[d * 128 + e] = w1[j];
    } else if (i < 40960) {
        int j = i - 32768; int e = j >> 7, h = j & 127;  // w2 [64][128]
        w2T[h * 64 + e] = w2[j];
    } else if (i < 45056) {
        int j = i - 40960; int d = j >> 6, e = j & 63;   // Wv [d][e] -> WvT [e][d]
        WvT[e * 64 + d] = Wv[j];
    } else if (i < 49152) {
        int j = i - 45056; int d = j >> 6, e = j & 63;   // WqT[d][e] = Wq[e][d]
        WqT[j] = Wq[e * 64 + d];
    }
}

// ---------------- per-iter: attention, fully MFMA ----------------
// One block = one 128-row chunk (grid 4096; b = ck>>5). 256 thr, 4 waves.
// Lane (m = lane&15, qd = lane>>4) of wave w holds xn rows w*32+tile*16+m,
// dims {qd*8..+8} (c=0) and {32+qd*8..+8} (c=1) -- exactly the 16x16x32
// B-operand layout B[k=c*32+qd*8+j][n=m].
// Phase 1: L[s][row] = MFMA(A=qkT frag [slot m][dim k], B=xn), slot exchange
// via shfl_xor(16), softmax over 7 slots, p -> p_lds bf16, xn -> xnT LDS
// (stride 140: 4-way max on the b16 scatter).
// Phase 2: pxn[s][e] = MFMA(A=p_lds frag, B=xnT frag), per-chunk partials.
__global__ __launch_bounds__(256) void attn_kernel(
    int first,
    const float* __restrict__ x,
    const float* __restrict__ lng, const float* __restrict__ lnb,
    ushortT* __restrict__ xnf,
    const float* __restrict__ qkT,   // [b][dim 64][slot 8] (slot 7 = 0)
    float* __restrict__ pxn_p, float* __restrict__ den_p) {
    int t = threadIdx.x;
    int ck = blockIdx.x, b = ck >> 5;
    int w = t >> 6, lane = t & 63, m = lane & 15, qd = lane >> 4;
    __shared__ float   qk_lds[512];
    __shared__ ushortT xnT[64 * 140];      // [e]*140 + row
    __shared__ ushortT p_lds[16][136];     // [slot][row]; rows 7..15 unused
    __shared__ float   den_w[4][8];

    for (int i = t; i < 512; i += 256) qk_lds[i] = qkT[b * 512 + i];

    unsigned xw[2][8];   // [tile][word]: words 0-3 = c0 dims, 4-7 = c1 dims
    if (first) {
        float4 g4[2][2], b4[2][2];
#pragma unroll
        for (int c = 0; c < 2; ++c) {
            g4[c][0] = *reinterpret_cast<const float4*>(lng + c * 32 + qd * 8);
            g4[c][1] = *reinterpret_cast<const float4*>(lng + c * 32 + qd * 8 + 4);
            b4[c][0] = *reinterpret_cast<const float4*>(lnb + c * 32 + qd * 8);
            b4[c][1] = *reinterpret_cast<const float4*>(lnb + c * 32 + qd * 8 + 4);
        }
#pragma unroll
        for (int tile = 0; tile < 2; ++tile) {
            long R = (long)ck * 128 + w * 32 + tile * 16 + m;
            float4 xa[2][2];
#pragma unroll
            for (int c = 0; c < 2; ++c) {
                xa[c][0] = *reinterpret_cast<const float4*>(x + R * 64 + c * 32 + qd * 8);
                xa[c][1] = *reinterpret_cast<const float4*>(x + R * 64 + c * 32 + qd * 8 + 4);
            }
            float s1 = 0.f, s2 = 0.f;
#pragma unroll
            for (int c = 0; c < 2; ++c)
#pragma unroll
                for (int h = 0; h < 2; ++h) {
                    float4 v = xa[c][h];
                    s1 += v.x + v.y + v.z + v.w;
                    s2 += v.x * v.x + v.y * v.y + v.z * v.z + v.w * v.w;
                }
            s1 += __shfl_xor(s1, 16); s2 += __shfl_xor(s2, 16);
            s1 += __shfl_xor(s1, 32); s2 += __shfl_xor(s2, 32);
            float mu = s1 * (1.f / 64.f);
            float var = s2 * (1.f / 64.f) - mu * mu;
            float rs = rsqrtf(var + LN_EPS);
#pragma unroll
            for (int c = 0; c < 2; ++c)
#pragma unroll
                for (int h = 0; h < 2; ++h) {
                    float n0 = (xa[c][h].x - mu) * rs * g4[c][h].x + b4[c][h].x;
                    float n1 = (xa[c][h].y - mu) * rs * g4[c][h].y + b4[c][h].y;
                    float n2 = (xa[c][h].z - mu) * rs * g4[c][h].z + b4[c][h].z;
                    float n3 = (xa[c][h].w - mu) * rs * g4[c][h].w + b4[c][h].w;
                    xw[tile][c * 4 + h * 2]     = (unsigned)f2bf(n0) | ((unsigned)f2bf(n1) << 16);
                    xw[tile][c * 4 + h * 2 + 1] = (unsigned)f2bf(n2) | ((unsigned)f2bf(n3) << 16);
                }
            ushortT* xp = xnf + (long)ck * 8192 + w * 2048 + tile * 1024 + lane * 16;
            *reinterpret_cast<uint4*>(xp) =
                make_uint4(xw[tile][0], xw[tile][1], xw[tile][2], xw[tile][3]);
            *reinterpret_cast<uint4*>(xp + 8) =
                make_uint4(xw[tile][4], xw[tile][5], xw[tile][6], xw[tile][7]);
        }
    } else {
#pragma unroll
        for (int tile = 0; tile < 2; ++tile) {
            const ushortT* xp = xnf + (long)ck * 8192 + w * 2048 + tile * 1024 + lane * 16;
            uint4 u0 = *reinterpret_cast<const uint4*>(xp);
            uint4 u1 = *reinterpret_cast<const uint4*>(xp + 8);
            xw[tile][0] = u0.x; xw[tile][1] = u0.y; xw[tile][2] = u0.z; xw[tile][3] = u0.w;
            xw[tile][4] = u1.x; xw[tile][5] = u1.y; xw[tile][6] = u1.z; xw[tile][7] = u1.w;
        }
    }
    __syncthreads();

    // qk A-frags: A[m=slot][k=c*32+qd*8+j]; slots >= 8 -> 0 (slot 7 zeroed in buf)
    short8 aq[2];
#pragma unroll
    for (int c = 0; c < 2; ++c) {
        short8 a = {};
        if (m < 8) {
#pragma unroll
            for (int j = 0; j < 8; ++j)
                a[j] = (short)f2bf(qk_lds[(c * 32 + qd * 8 + j) * 8 + m]);
        }
        aq[c] = a;
    }

    float dreg03[4] = {0.f, 0.f, 0.f, 0.f};
    float dreg46[3] = {0.f, 0.f, 0.f};
#pragma unroll
    for (int tile = 0; tile < 2; ++tile) {
        int row = w * 32 + tile * 16 + m;
        // stash xn into transposed LDS (phase-2 B source)
#pragma unroll
        for (int c = 0; c < 2; ++c)
#pragma unroll
            for (int j = 0; j < 8; ++j) {
                int e = c * 32 + qd * 8 + j;
                xnT[e * 140 + row] =
                    (ushortT)(xw[tile][c * 4 + (j >> 1)] >> ((j & 1) * 16));
            }
        uint4v b0 = {xw[tile][0], xw[tile][1], xw[tile][2], xw[tile][3]};
        uint4v b1 = {xw[tile][4], xw[tile][5], xw[tile][6], xw[tile][7]};
        floatx4 acc = (floatx4){0.f, 0.f, 0.f, 0.f};
        acc = __builtin_amdgcn_mfma_f32_16x16x32_bf16(aq[0],
                  __builtin_bit_cast(short8, b0), acc, 0, 0, 0);
        acc = __builtin_amdgcn_mfma_f32_16x16x32_bf16(aq[1],
                  __builtin_bit_cast(short8, b1), acc, 0, 0, 0);
        // lane (m=row-in-tile, qd) holds slots qd*4+r; exchange qd pairs
        float own[4], par[4];
#pragma unroll
        for (int r = 0; r < 4; ++r) { own[r] = acc[r]; par[r] = __shfl_xor(acc[r], 16); }
        float lgA[4], lgB[4];   // lgA = slots 0-3, lgB = slots 4-7 (valid qd<2)
#pragma unroll
        for (int r = 0; r < 4; ++r) {
            lgA[r] = (qd & 1) ? par[r] : own[r];
            lgB[r] = (qd & 1) ? own[r] : par[r];
        }
        float mx = fmaxf(fmaxf(fmaxf(lgA[0], lgA[1]), fmaxf(lgA[2], lgA[3])),
                         fmaxf(fmaxf(lgB[0], lgB[1]), lgB[2]));
        float eA[4], eB[3], sum = 0.f;
#pragma unroll
        for (int r = 0; r < 4; ++r) { eA[r] = __expf(lgA[r] - mx); sum += eA[r]; }
#pragma unroll
        for (int r = 0; r < 3; ++r) { eB[r] = __expf(lgB[r] - mx); sum += eB[r]; }
        float inv = 1.f / sum;
        if (qd == 0) {
#pragma unroll
            for (int r = 0; r < 4; ++r) {
                ushortT pb = f2bf(eA[r] * inv + EPS_ATTN);
                p_lds[r][row] = pb;
                dreg03[r] += bf2f(pb);
            }
        } else if (qd == 1) {
#pragma unroll
            for (int r = 0; r < 3; ++r) {
                ushortT pb = f2bf(eB[r] * inv + EPS_ATTN);
                p_lds[4 + r][row] = pb;
                dreg46[r] += bf2f(pb);
            }
        }
    }
    // den: reduce over the 16 m-lanes (stays within qd group)
#pragma unroll
    for (int off = 1; off < 16; off <<= 1) {
#pragma unroll
        for (int r = 0; r < 4; ++r) dreg03[r] += __shfl_xor(dreg03[r], off);
#pragma unroll
        for (int r = 0; r < 3; ++r) dreg46[r] += __shfl_xor(dreg46[r], off);
    }
    if (m == 0 && qd == 0) {
#pragma unroll
        for (int r = 0; r < 4; ++r) den_w[w][r] = dreg03[r];
    } else if (m == 0 && qd == 1) {
#pragma unroll
        for (int r = 0; r < 3; ++r) den_w[w][4 + r] = dreg46[r];
    }
    __syncthreads();

    // phase 2: pxn[s][e]; wave w owns e-tile w*16..+16
    floatx4 acc2 = (floatx4){0.f, 0.f, 0.f, 0.f};
#pragma unroll
    for (int ks = 0; ks < 4; ++ks) {
        short8 ap = *reinterpret_cast<const short8*>(&p_lds[m][ks * 32 + qd * 8]);
        const ushortT* xp = xnT + (w * 16 + m) * 140 + ks * 32 + qd * 8;
        uint2 u0 = *reinterpret_cast<const uint2*>(xp);
        uint2 u1 = *reinterpret_cast<const uint2*>(xp + 4);
        uint4v bb = {u0.x, u0.y, u1.x, u1.y};
        acc2 = __builtin_amdgcn_mfma_f32_16x16x32_bf16(ap,
                   __builtin_bit_cast(short8, bb), acc2, 0, 0, 0);
    }
#pragma unroll
    for (int r = 0; r < 4; ++r) {
        int s = qd * 4 + r;
        if (s < 7) pxn_p[((long)ck * 7 + s) * 64 + w * 16 + m] = acc2[r];
    }
    if (t < 7) den_p[ck * 8 + t] = den_w[0][t] + den_w[1][t] + den_w[2][t] + den_w[3][t];
}

// ---------------- per-slot pipeline: reduce+Wv+GRU+LN+MLP then LN+q+qkT ----
// 896 blocks (one per (b,s)), 192 threads (3 waves for the GRU matvec).
__global__ __launch_bounds__(192) void slot_update_q(
    int mode,
    const float* __restrict__ pxn_p, const float* __restrict__ den_p,
    float* __restrict__ slots,
    const float* __restrict__ nbg, const float* __restrict__ nfg,
    const float* __restrict__ bgmu, const float* __restrict__ bgls,
    const float* __restrict__ fmu, const float* __restrict__ fls,
    const float* __restrict__ WihT, const float* __restrict__ WhhT,
    const float* __restrict__ bih, const float* __restrict__ bhh,
    const float* __restrict__ lng, const float* __restrict__ lnb,
    const float* __restrict__ w1T, const float* __restrict__ b1,
    const float* __restrict__ w2T, const float* __restrict__ b2,
    const float* __restrict__ WvT, const float* __restrict__ WqT,
    const float* __restrict__ Wk,
    const float* __restrict__ sg, const float* __restrict__ sb,
    float* __restrict__ qkT, float* __restrict__ outp) {
    int bs = blockIdx.x, t = threadIdx.x;
    int b = bs / 7, s = bs % 7;
    __shared__ float pxnL[64], hprevL[64], updL[64], giL[192], ghL[192],
                     mnL[64], m1L[128], xnL[64], qL[64];
    float res = 0.f, dsum = 0.f;
    if (mode == 0) {
        if (t < 64) {
            if (s == 0) res = bgmu[t] + __expf(bgls[t]) * nbg[b * 64 + t];
            else        res = fmu[t]  + __expf(fls[t])  * nfg[(b * 6 + s - 1) * 64 + t];
        }
    } else {
        if (t < 64) {
            float psum = 0.f;
#pragma unroll 8
            for (int c = 0; c < 32; ++c) {
                psum += pxn_p[((long)(b * 32 + c) * 7 + s) * 64 + t];
                dsum += den_p[(b * 32 + c) * 8 + s];
            }
            pxnL[t]   = psum;
            hprevL[t] = slots[bs * 64 + t];
        }
        __syncthreads();
        if (t < 64) {
            float nm = 0.f;
#pragma unroll 8
            for (int e = 0; e < 64; ++e) nm += pxnL[e] * WvT[e * 64 + t];
            updL[t] = nm / dsum;
        }
        __syncthreads();
        {   // GRU gates, 192-wide
            float a = bih[t], h2 = bhh[t];
#pragma unroll 8
            for (int d = 0; d < 64; ++d) {
                a  += updL[d]   * WihT[d * 192 + t];
                h2 += hprevL[d] * WhhT[d * 192 + t];
            }
            giL[t] = a; ghL[t] = h2;
        }
        __syncthreads();
        if (t < 64) {
            float r = 1.f / (1.f + __expf(-(giL[t] + ghL[t])));
            float z = 1.f / (1.f + __expf(-(giL[64 + t] + ghL[64 + t])));
            float n = tanhf(giL[128 + t] + r * ghL[128 + t]);
            float h = (1.f - z) * n + z * hprevL[t];
            res = h;
            float mu, var;
            wave_stats64(h, mu, var);
            mnL[t] = (h - mu) * rsqrtf(var + LN_EPS) * lng[t] + lnb[t];
        }
        __syncthreads();
        if (t < 128) {
            float a = b1[t];
#pragma unroll 8
            for (int d = 0; d < 64; ++d) a += mnL[d] * w1T[d * 128 + t];
            m1L[t] = fmaxf(a, 0.f);
        }
        __syncthreads();
        if (t < 64) {
            float a = b2[t];
#pragma unroll 8
            for (int h2 = 0; h2 < 128; ++h2) a += m1L[h2] * w2T[h2 * 64 + t];
            res += a;
        }
    }
    if (t < 64) slots[bs * 64 + t] = res;
    if (mode == 2) {
        if (t < 64) outp[bs * 64 + t] = res;
        return;
    }
    // slot LN -> q (scale folded) -> qk = Wk^T q, stored transposed [dim][8]
    if (t < 64) {
        float mu, var;
        wave_stats64(res, mu, var);
        xnL[t] = (res - mu) * rsqrtf(var + LN_EPS) * sg[t] + sb[t];
    }
    __syncthreads();
    if (t < 64) {
        float q = 0.f;
#pragma unroll 8
        for (int d = 0; d < 64; ++d) q += xnL[d] * WqT[d * 64 + t];
        qL[t] = q * 0.125f;
    }
    __syncthreads();
    if (t < 64) {
        float qk = 0.f;
#pragma unroll 8
        for (int e = 0; e < 64; ++e) qk += qL[e] * Wk[e * 64 + t];
        qkT[b * 512 + t * 8 + s] = qk;
        if (s == 0) qkT[b * 512 + t * 8 + 7] = 0.f;
    }
}

// ---------------- launcher ----------------
extern "C" void kernel_launch(void* const* d_in, const int* in_sizes, int n_in,
                              void* d_out, int out_size, void* d_ws, size_t ws_size,
                              hipStream_t stream) {
    const float* inputs    = (const float*)d_in[0];
    const float* noise_bg  = (const float*)d_in[1];
    const float* noise_fg  = (const float*)d_in[2];
    const float* ln_in_g   = (const float*)d_in[3];
    const float* ln_in_b   = (const float*)d_in[4];
    const float* ln_slot_g = (const float*)d_in[5];
    const float* ln_slot_b = (const float*)d_in[6];
    const float* ln_mlp_g  = (const float*)d_in[7];
    const float* ln_mlp_b  = (const float*)d_in[8];
    const float* Wq        = (const float*)d_in[9];
    const float* Wk        = (const float*)d_in[10];
    const float* Wv        = (const float*)d_in[11];
    const float* W_ih      = (const float*)d_in[12];
    const float* W_hh      = (const float*)d_in[13];
    const float* b_ih      = (const float*)d_in[14];
    const float* b_hh      = (const float*)d_in[15];
    const float* mlp_w1    = (const float*)d_in[16];
    const float* mlp_b1    = (const float*)d_in[17];
    const float* mlp_w2    = (const float*)d_in[18];
    const float* mlp_b2    = (const float*)d_in[19];
    const float* sbg_mu    = (const float*)d_in[20];
    const float* sbg_ls    = (const float*)d_in[21];
    const float* s_mu      = (const float*)d_in[22];
    const float* s_ls      = (const float*)d_in[23];

    char* ws = (char*)d_ws;
    size_t off = 0;
    auto alloc = [&](size_t bytes) {
        void* p = ws + off;
        off += (bytes + 255) & ~(size_t)255;
        return p;
    };
    ushortT* xnf   = (ushortT*)alloc((size_t)BB * NN * 64 * 2);   // 64 MiB bf16 xn
    float* slots   = (float*)alloc(57344 * 4);
    float* qkT     = (float*)alloc((size_t)BB * 512 * 4);
    float* pxn_p   = (float*)alloc((size_t)4096 * 7 * 64 * 4);    // 7.34 MB
    float* den_p   = (float*)alloc(4096 * 8 * 4);
    float* WihT    = (float*)alloc(12288 * 4);
    float* WhhT    = (float*)alloc(12288 * 4);
    float* w1T     = (float*)alloc(8192 * 4);
    float* w2T     = (float*)alloc(8192 * 4);
    float* WvT     = (float*)alloc(4096 * 4);
    float* WqT     = (float*)alloc(4096 * 4);
    if (off > ws_size) return;

    prep_w<<<192, 256, 0, stream>>>(W_ih, W_hh, mlp_w1, mlp_w2, Wv, Wq,
                                    WihT, WhhT, w1T, w2T, WvT, WqT);
    slot_update_q<<<896, 192, 0, stream>>>(0, pxn_p, den_p, slots,
                                           noise_bg, noise_fg, sbg_mu, sbg_ls,
                                           s_mu, s_ls, WihT, WhhT, b_ih, b_hh,
                                           ln_mlp_g, ln_mlp_b, w1T, mlp_b1,
                                           w2T, mlp_b2, WvT, WqT, Wk,
                                           ln_slot_g, ln_slot_b,
                                           qkT, (float*)d_out);
    for (int it = 0; it < N_ITERS; ++it) {
        attn_kernel<<<4096, 256, 0, stream>>>((it == 0) ? 1 : 0,
                                              inputs, ln_in_g, ln_in_b,
                                              xnf, qkT, pxn_p, den_p);
        slot_update_q<<<896, 192, 0, stream>>>((it == N_ITERS - 1) ? 2 : 1,
                                               pxn_p, den_p, slots,
                                               noise_bg, noise_fg, sbg_mu, sbg_ls,
                                               s_mu, s_ls, WihT, WhhT, b_ih, b_hh,
                                               ln_mlp_g, ln_mlp_b, w1T, mlp_b1,
                                               w2T, mlp_b2, WvT, WqT, Wk,
                                               ln_slot_g, ln_slot_b,
                                               qkT, (float*)d_out);
    }
}